// Round 4
// baseline (411.960 us; speedup 1.0000x reference)
//
#include <hip/hip_runtime.h>
#include <cstdint>

typedef __bf16 bf16x8 __attribute__((ext_vector_type(8)));
typedef float f32x16 __attribute__((ext_vector_type(16)));

#define LOG2E 1.44269504088896340736f

static __device__ __forceinline__ ushort f2bf(float f) {
  uint u = __builtin_bit_cast(uint, f);
  u = u + 0x7FFFu + ((u >> 16) & 1u);   // RNE
  return (ushort)(u >> 16);
}

static __device__ __forceinline__ uint cvtpk_bf16(float lo, float hi) {
  uint r;
  asm("v_cvt_pk_bf16_f32 %0, %1, %2" : "=v"(r) : "v"(lo), "v"(hi));
  return r;
}

static __device__ __forceinline__ void plswap(uint& a, uint& b) {
  asm("v_permlane32_swap_b32 %0, %1" : "+v"(a), "+v"(b));
}

#if __has_builtin(__builtin_amdgcn_exp2f)
#define EXP2(x) __builtin_amdgcn_exp2f(x)
#else
#define EXP2(x) exp2f(x)
#endif

// ---------------------------------------------------------------------------
// Workspace layouts (all bf16 as ushort):
//   qs : [b][32 d][4096 m]                      (2 MB)
//   kz : [b][128 T][frag j(2)][lane(64)][i(8)]  (2 MB)  K-tile fragment-major
//   vz : [b][128 T][frag j(16)][lane(64)][i(8)] (16 MB) V-tile fragment-major
// A-frag convention (verified R1): lane holds A[row=l31][k=8*hi+i].
// ---------------------------------------------------------------------------

__global__ __launch_bounds__(256, 2) void proj_qkv(
    const float* __restrict__ x,
    const float* __restrict__ Wq, const float* __restrict__ bq,
    const float* __restrict__ Wk, const float* __restrict__ bk,
    const float* __restrict__ Wv, const float* __restrict__ bv,
    ushort* __restrict__ qo, ushort* __restrict__ ko, ushort* __restrict__ vo)
{
  __shared__ float xs[32][256];   // [c][n]
  __shared__ float wt[32][64];    // [c][d] (transposed W chunk)

  const int tid = threadIdx.x;
  const int nt = blockIdx.x, b = blockIdx.y, dt = blockIdx.z;
  const int n0 = nt * 256;
  const int nthr = tid & 31;
  const int dthr = tid >> 5;

  float acc[8][8];
#pragma unroll
  for (int i = 0; i < 8; ++i)
#pragma unroll
    for (int j = 0; j < 8; ++j) acc[i][j] = 0.f;

  const float* xb = x + (size_t)b * 256 * 4096;

  for (int kc = 0; kc < 8; ++kc) {
    const int c0 = kc * 32;
    __syncthreads();
#pragma unroll
    for (int r = 0; r < 8; ++r) {
      int id = r * 256 + tid;
      int c = id >> 6, pos = (id & 63) * 4;
      float4 v = *(const float4*)(xb + (size_t)(c0 + c) * 4096 + n0 + pos);
      *(float4*)&xs[c][pos] = v;
    }
#pragma unroll
    for (int r = 0; r < 2; ++r) {
      int id = r * 256 + tid;
      int d = id >> 3, c4 = (id & 7) * 4;
      int grow = dt * 64 + d;
      const float* wrow;
      float scale = 1.f;
      if (dt == 0) {
        if (grow < 32) { wrow = Wq + (size_t)grow * 256; scale = LOG2E; }
        else           { wrow = Wk + (size_t)(grow - 32) * 256; }
      } else {
        wrow = Wv + (size_t)(grow - 64) * 256;
      }
      float4 v = *(const float4*)(wrow + c0 + c4);
      wt[c4 + 0][d] = v.x * scale;
      wt[c4 + 1][d] = v.y * scale;
      wt[c4 + 2][d] = v.z * scale;
      wt[c4 + 3][d] = v.w * scale;
    }
    __syncthreads();

#pragma unroll
    for (int cc = 0; cc < 32; ++cc) {
      float4 xv0 = *(const float4*)&xs[cc][nthr * 4];
      float4 xv1 = *(const float4*)&xs[cc][nthr * 4 + 128];
      float4 wv0 = *(const float4*)&wt[cc][dthr * 8];
      float4 wv1 = *(const float4*)&wt[cc][dthr * 8 + 4];
      float wr[8] = {wv0.x, wv0.y, wv0.z, wv0.w, wv1.x, wv1.y, wv1.z, wv1.w};
      float xr[8] = {xv0.x, xv0.y, xv0.z, xv0.w, xv1.x, xv1.y, xv1.z, xv1.w};
#pragma unroll
      for (int dd = 0; dd < 8; ++dd)
#pragma unroll
        for (int nn = 0; nn < 8; ++nn)
          acc[dd][nn] = fmaf(wr[dd], xr[nn], acc[dd][nn]);
    }
  }

  // ---- epilogue ----
  if (dt == 0 && dthr < 4) {
#pragma unroll
    for (int dd = 0; dd < 8; ++dd) {
      int grow = dthr * 8 + dd;
      ushort* dst = qo + ((size_t)b * 32 + grow) * 4096;
      float bias = bq[grow] * LOG2E;
      ushort4 w0, w1;
      w0.x = f2bf(acc[dd][0] + bias); w0.y = f2bf(acc[dd][1] + bias);
      w0.z = f2bf(acc[dd][2] + bias); w0.w = f2bf(acc[dd][3] + bias);
      w1.x = f2bf(acc[dd][4] + bias); w1.y = f2bf(acc[dd][5] + bias);
      w1.z = f2bf(acc[dd][6] + bias); w1.w = f2bf(acc[dd][7] + bias);
      *(ushort4*)(dst + n0 + nthr * 4) = w0;
      *(ushort4*)(dst + n0 + nthr * 4 + 128) = w1;
    }
  } else if (dt == 0) {
    const int dkbase = (dthr - 4) * 8;
    const int j = dkbase >> 4;
    const int khi = (dkbase >> 3) & 1;
    float bias[8];
#pragma unroll
    for (int dd = 0; dd < 8; ++dd) bias[dd] = bk[dkbase + dd];
    const size_t kzb = (size_t)b * 131072;
#pragma unroll
    for (int nn = 0; nn < 8; ++nn) {
      int n = n0 + nthr * 4 + (nn & 3) + (nn >> 2) * 128;
      int kk = n & 31, T = n >> 5;
      size_t base = kzb + (size_t)T * 1024 + j * 512 + khi * 256 + kk * 8;
      ushort4 a, bb;
      a.x = f2bf(acc[0][nn] + bias[0]); a.y = f2bf(acc[1][nn] + bias[1]);
      a.z = f2bf(acc[2][nn] + bias[2]); a.w = f2bf(acc[3][nn] + bias[3]);
      bb.x = f2bf(acc[4][nn] + bias[4]); bb.y = f2bf(acc[5][nn] + bias[5]);
      bb.z = f2bf(acc[6][nn] + bias[6]); bb.w = f2bf(acc[7][nn] + bias[7]);
      *(ushort4*)(ko + base) = a;
      *(ushort4*)(ko + base + 4) = bb;
    }
  } else {
    const int cbase = (dt - 1) * 64 + dthr * 8;
    const int kk4 = (nthr * 4) & 31;
    const int T0 = (n0 + nthr * 4) >> 5;
    const int vhi = (kk4 >> 3) & 1;
    const int i4 = kk4 & 7;
    const size_t vzb = (size_t)b * 1048576;
#pragma unroll
    for (int dd = 0; dd < 8; ++dd) {
      int c = cbase + dd;
      float bias = bv[c];
      int jj = (c >> 5) * 2 + (kk4 >> 4);
      int l = c & 31;
      size_t off0 = vzb + (size_t)T0 * 8192 + (size_t)jj * 512 + vhi * 256 + l * 8 + i4;
      ushort4 w0, w1;
      w0.x = f2bf(acc[dd][0] + bias); w0.y = f2bf(acc[dd][1] + bias);
      w0.z = f2bf(acc[dd][2] + bias); w0.w = f2bf(acc[dd][3] + bias);
      w1.x = f2bf(acc[dd][4] + bias); w1.y = f2bf(acc[dd][5] + bias);
      w1.z = f2bf(acc[dd][6] + bias); w1.w = f2bf(acc[dd][7] + bias);
      *(ushort4*)(vo + off0) = w0;
      *(ushort4*)(vo + off0 + 4 * 8192) = w1;
    }
  }
}

// ---------------------------------------------------------------------------
// online softmax + P packing for one 32-m set. All acc indices compile-time
// (inlined, unrolled) — rule #20.
// ---------------------------------------------------------------------------
static __device__ __forceinline__ void softmax_pack(
    f32x16& s, float& mrun, float& lsum, f32x16 (&acc)[8],
    bf16x8& pb0o, bf16x8& pb1o)
{
  float pm = s[0];
#pragma unroll
  for (int r = 1; r < 16; ++r) pm = fmaxf(pm, s[r]);
  pm = fmaxf(pm, __shfl_xor(pm, 32));

  if (!__all(pm <= mrun + 8.0f)) {              // defer-max (T13), log2 domain
    float mnew = fmaxf(mrun, pm);
    float a = EXP2(mrun - mnew);
    mrun = mnew;
    lsum *= a;
#pragma unroll
    for (int t8 = 0; t8 < 8; ++t8)
#pragma unroll
      for (int r = 0; r < 16; ++r) acc[t8][r] *= a;
  }

  float p[16];
  float ps = 0.f;
#pragma unroll
  for (int r = 0; r < 16; ++r) { p[r] = EXP2(s[r] - mrun); ps += p[r]; }
  ps += __shfl_xor(ps, 32);
  lsum += ps;

  uint pw[8];
#pragma unroll
  for (int j = 0; j < 8; ++j) pw[j] = cvtpk_bf16(p[2 * j], p[2 * j + 1]);
  plswap(pw[0], pw[2]); plswap(pw[1], pw[3]);
  plswap(pw[4], pw[6]); plswap(pw[5], pw[7]);
  union { uint u[4]; bf16x8 v; } pb0u, pb1u;
  pb0u.u[0] = pw[0]; pb0u.u[1] = pw[1]; pb0u.u[2] = pw[2]; pb0u.u[3] = pw[3];
  pb1u.u[0] = pw[4]; pb1u.u[1] = pw[5]; pb1u.u[2] = pw[6]; pb1u.u[3] = pw[7];
  pb0o = pb0u.v; pb1o = pb1u.v;
}

// ---------------------------------------------------------------------------
// Kernel 2: fused flash attention + residual.
// 64 m per wave (2 B-frag sets) so each V A-fragment feeds 2 MFMAs (2x
// arithmetic intensity per L2 byte — R3 showed L2-BW-bound). Key-split x2.
// 512 blocks = 2 resident/CU at 1 wave/SIMD (acc=256 regs). Merge epilogue
// in two passes reusing a 32 KB LDS buffer.
// ---------------------------------------------------------------------------
__global__ __launch_bounds__(128, 1) void attn_fused(
    const ushort* __restrict__ qs, const ushort* __restrict__ kz,
    const ushort* __restrict__ vz, const float* __restrict__ x,
    const float* __restrict__ gamma, float* __restrict__ out)
{
  __shared__ float xch[2][4][16][64];   // 32 KB, reused across two passes
  __shared__ float sml[2][2][2][64];    // [w][set][{m,l}][lane], 4 KB

  const int wg = blockIdx.x;                      // 0..511
  const int swz = (wg & 7) * 64 + (wg >> 3);      // one batch per XCD
  const int b = swz >> 6, mt = swz & 63;
  const int tid = threadIdx.x;
  const int w = tid >> 6, lane = tid & 63;
  const int l31 = lane & 31, hi = lane >> 5;
  const int m0 = mt * 64 + l31;                   // set0 column
  const int m1 = m0 + 32;                         // set1 column

  // resident Q B-frags (2 sets x 2 k-frags)
  const ushort* qc0 = qs + (size_t)b * 131072 + m0;
  bf16x8 qf0, qf1, qf2, qf3;
  {
    union { ushort s[8]; bf16x8 v; } u0, u1, u2, u3;
#pragma unroll
    for (int i = 0; i < 8; ++i) {
      u0.s[i] = qc0[(size_t)(8 * hi + i) * 4096];
      u1.s[i] = qc0[(size_t)(16 + 8 * hi + i) * 4096];
      u2.s[i] = qc0[32 + (size_t)(8 * hi + i) * 4096];
      u3.s[i] = qc0[32 + (size_t)(16 + 8 * hi + i) * 4096];
    }
    qf0 = u0.v; qf1 = u1.v; qf2 = u2.v; qf3 = u3.v;
  }

  const ushort* kb = kz + (size_t)b * 131072 + (size_t)w * 64 * 1024;
  const ushort* vb = vz + (size_t)b * 1048576 + (size_t)w * 64 * 8192;

  f32x16 acc0[8], acc1[8];
#pragma unroll
  for (int t8 = 0; t8 < 8; ++t8)
#pragma unroll
    for (int r = 0; r < 16; ++r) { acc0[t8][r] = 0.f; acc1[t8][r] = 0.f; }

  float mrun0 = -1e30f, lsum0 = 0.f;
  float mrun1 = -1e30f, lsum1 = 0.f;

  for (int t = 0; t < 64; ++t) {
    const ushort* kt = kb + t * 1024;
    bf16x8 ka0 = *(const bf16x8*)(kt + lane * 8);
    bf16x8 ka1 = *(const bf16x8*)(kt + 512 + lane * 8);

    f32x16 s0, s1;
#pragma unroll
    for (int r = 0; r < 16; ++r) { s0[r] = 0.f; s1[r] = 0.f; }
    s0 = __builtin_amdgcn_mfma_f32_32x32x16_bf16(ka0, qf0, s0, 0, 0, 0);
    s0 = __builtin_amdgcn_mfma_f32_32x32x16_bf16(ka1, qf1, s0, 0, 0, 0);
    s1 = __builtin_amdgcn_mfma_f32_32x32x16_bf16(ka0, qf2, s1, 0, 0, 0);
    s1 = __builtin_amdgcn_mfma_f32_32x32x16_bf16(ka1, qf3, s1, 0, 0, 0);

    bf16x8 pA0, pA1, pB0, pB1;
    softmax_pack(s0, mrun0, lsum0, acc0, pA0, pA1);
    softmax_pack(s1, mrun1, lsum1, acc1, pB0, pB1);

    // PV: each V A-frag feeds BOTH m-sets (2x intensity per L2 byte)
    const ushort* vt = vb + (size_t)t * 8192;
#pragma unroll
    for (int t8 = 0; t8 < 8; ++t8) {
      bf16x8 va0 = *(const bf16x8*)(vt + (t8 * 2 + 0) * 512 + lane * 8);
      bf16x8 va1 = *(const bf16x8*)(vt + (t8 * 2 + 1) * 512 + lane * 8);
      acc0[t8] = __builtin_amdgcn_mfma_f32_32x32x16_bf16(va0, pA0, acc0[t8], 0, 0, 0);
      acc1[t8] = __builtin_amdgcn_mfma_f32_32x32x16_bf16(va0, pB0, acc1[t8], 0, 0, 0);
      acc0[t8] = __builtin_amdgcn_mfma_f32_32x32x16_bf16(va1, pA1, acc0[t8], 0, 0, 0);
      acc1[t8] = __builtin_amdgcn_mfma_f32_32x32x16_bf16(va1, pB1, acc1[t8], 0, 0, 0);
    }
  }

  // ---- merge the two key-split partials (two passes over 32 KB xch) ----
  sml[w][0][0][lane] = mrun0; sml[w][0][1][lane] = lsum0;
  sml[w][1][0][lane] = mrun1; sml[w][1][1][lane] = lsum1;
  __syncthreads();
  const float mo0 = sml[1 - w][0][0][lane], lo0 = sml[1 - w][0][1][lane];
  const float mo1 = sml[1 - w][1][0][lane], lo1 = sml[1 - w][1][1][lane];
  const float ms0 = fmaxf(mrun0, mo0);
  const float aw0 = EXP2(mrun0 - ms0), ao0 = EXP2(mo0 - ms0);
  const float lt0 = lsum0 * aw0 + lo0 * ao0;
  const float ms1 = fmaxf(mrun1, mo1);
  const float aw1 = EXP2(mrun1 - ms1), ao1 = EXP2(mo1 - ms1);
  const float lt1 = lsum1 * aw1 + lo1 * ao1;
#pragma unroll
  for (int t8 = 0; t8 < 8; ++t8)
#pragma unroll
    for (int r = 0; r < 16; ++r) { acc0[t8][r] *= aw0; acc1[t8][r] *= aw1; }

  const float inv0 = 1.0f / lt0, inv1 = 1.0f / lt1;
  const float g = gamma[0];
  const float* xc0 = x + (size_t)b * 256 * 4096 + m0;
  float* oc0 = out + (size_t)b * 256 * 4096 + m0;

  // ---- pass A: set0 ----
  if (w == 0) {
#pragma unroll
    for (int q = 0; q < 4; ++q)
#pragma unroll
      for (int r = 0; r < 16; ++r)
        xch[0][q][r][lane] = acc0[4 + q][r];
  } else {
#pragma unroll
    for (int q = 0; q < 4; ++q)
#pragma unroll
      for (int r = 0; r < 16; ++r)
        xch[1][q][r][lane] = acc0[q][r];
  }
  __syncthreads();
  if (w == 0) {
#pragma unroll
    for (int q = 0; q < 4; ++q)
#pragma unroll
      for (int r = 0; r < 16; ++r) {
        float val = acc0[q][r] + xch[1][q][r][lane];
        int c = q * 32 + (r & 3) + 8 * (r >> 2) + 4 * hi;
        oc0[(size_t)c * 4096] = g * (val * inv0) + xc0[(size_t)c * 4096];
      }
  } else {
#pragma unroll
    for (int q = 0; q < 4; ++q)
#pragma unroll
      for (int r = 0; r < 16; ++r) {
        float val = acc0[4 + q][r] + xch[0][q][r][lane];
        int c = (4 + q) * 32 + (r & 3) + 8 * (r >> 2) + 4 * hi;
        oc0[(size_t)c * 4096] = g * (val * inv0) + xc0[(size_t)c * 4096];
      }
  }
  __syncthreads();   // xch reuse hazard: pass-B writes must wait for pass-A reads

  // ---- pass B: set1 ----
  if (w == 0) {
#pragma unroll
    for (int q = 0; q < 4; ++q)
#pragma unroll
      for (int r = 0; r < 16; ++r)
        xch[0][q][r][lane] = acc1[4 + q][r];
  } else {
#pragma unroll
    for (int q = 0; q < 4; ++q)
#pragma unroll
      for (int r = 0; r < 16; ++r)
        xch[1][q][r][lane] = acc1[q][r];
  }
  __syncthreads();
  if (w == 0) {
#pragma unroll
    for (int q = 0; q < 4; ++q)
#pragma unroll
      for (int r = 0; r < 16; ++r) {
        float val = acc1[q][r] + xch[1][q][r][lane];
        int c = q * 32 + (r & 3) + 8 * (r >> 2) + 4 * hi;
        oc0[32 + (size_t)c * 4096] = g * (val * inv1) + xc0[32 + (size_t)c * 4096];
      }
  } else {
#pragma unroll
    for (int q = 0; q < 4; ++q)
#pragma unroll
      for (int r = 0; r < 16; ++r) {
        float val = acc1[4 + q][r] + xch[0][q][r][lane];
        int c = (4 + q) * 32 + (r & 3) + 8 * (r >> 2) + 4 * hi;
        oc0[32 + (size_t)c * 4096] = g * (val * inv1) + xc0[32 + (size_t)c * 4096];
      }
  }
}

extern "C" void kernel_launch(void* const* d_in, const int* in_sizes, int n_in,
                              void* d_out, int out_size, void* d_ws, size_t ws_size,
                              hipStream_t stream) {
  const float* x  = (const float*)d_in[0];
  const float* Wq = (const float*)d_in[1];
  const float* bq = (const float*)d_in[2];
  const float* Wk = (const float*)d_in[3];
  const float* bk = (const float*)d_in[4];
  const float* Wv = (const float*)d_in[5];
  const float* bv = (const float*)d_in[6];
  const float* gm = (const float*)d_in[7];
  float* out = (float*)d_out;

  ushort* qs = (ushort*)d_ws;
  ushort* kzp = qs + (size_t)8 * 131072;
  ushort* vzp = kzp + (size_t)8 * 131072;

  proj_qkv<<<dim3(16, 8, 5), 256, 0, stream>>>(x, Wq, bq, Wk, bk, Wv, bv, qs, kzp, vzp);
  attn_fused<<<dim3(512), 128, 0, stream>>>(qs, kzp, vzp, x, gm, out);
}

// Round 5
// 304.388 us; speedup vs baseline: 1.3534x; 1.3534x over previous
//
#include <hip/hip_runtime.h>
#include <cstdint>

typedef __bf16 bf16x8 __attribute__((ext_vector_type(8)));
typedef float f32x16 __attribute__((ext_vector_type(16)));

#define LOG2E 1.44269504088896340736f

static __device__ __forceinline__ ushort f2bf(float f) {
  uint u = __builtin_bit_cast(uint, f);
  u = u + 0x7FFFu + ((u >> 16) & 1u);   // RNE
  return (ushort)(u >> 16);
}

static __device__ __forceinline__ uint cvtpk_bf16(float lo, float hi) {
  uint r;
  asm("v_cvt_pk_bf16_f32 %0, %1, %2" : "=v"(r) : "v"(lo), "v"(hi));
  return r;
}

static __device__ __forceinline__ void plswap(uint& a, uint& b) {
  asm("v_permlane32_swap_b32 %0, %1" : "+v"(a), "+v"(b));
}

#if __has_builtin(__builtin_amdgcn_exp2f)
#define EXP2(x) __builtin_amdgcn_exp2f(x)
#else
#define EXP2(x) exp2f(x)
#endif

// ---------------------------------------------------------------------------
// Workspace layouts (all bf16 as ushort):
//   qs : [b][32 d][4096 m]                      (2 MB)
//   kz : [b][128 T][frag j(2)][lane(64)][i(8)]  (2 MB)  K-tile fragment-major
//   vz : [b][128 T][frag j(16)][lane(64)][i(8)] (16 MB) V-tile fragment-major
// A-frag convention (verified R1): lane holds A[row=l31][k=8*hi+i].
// ---------------------------------------------------------------------------

__global__ __launch_bounds__(256, 2) void proj_qkv(
    const float* __restrict__ x,
    const float* __restrict__ Wq, const float* __restrict__ bq,
    const float* __restrict__ Wk, const float* __restrict__ bk,
    const float* __restrict__ Wv, const float* __restrict__ bv,
    ushort* __restrict__ qo, ushort* __restrict__ ko, ushort* __restrict__ vo)
{
  __shared__ float xs[32][256];   // [c][n]
  __shared__ float wt[32][64];    // [c][d] (transposed W chunk)

  const int tid = threadIdx.x;
  const int nt = blockIdx.x, b = blockIdx.y, dt = blockIdx.z;
  const int n0 = nt * 256;
  const int nthr = tid & 31;
  const int dthr = tid >> 5;

  float acc[8][8];
#pragma unroll
  for (int i = 0; i < 8; ++i)
#pragma unroll
    for (int j = 0; j < 8; ++j) acc[i][j] = 0.f;

  const float* xb = x + (size_t)b * 256 * 4096;

  for (int kc = 0; kc < 8; ++kc) {
    const int c0 = kc * 32;
    __syncthreads();
#pragma unroll
    for (int r = 0; r < 8; ++r) {
      int id = r * 256 + tid;
      int c = id >> 6, pos = (id & 63) * 4;
      float4 v = *(const float4*)(xb + (size_t)(c0 + c) * 4096 + n0 + pos);
      *(float4*)&xs[c][pos] = v;
    }
#pragma unroll
    for (int r = 0; r < 2; ++r) {
      int id = r * 256 + tid;
      int d = id >> 3, c4 = (id & 7) * 4;
      int grow = dt * 64 + d;
      const float* wrow;
      float scale = 1.f;
      if (dt == 0) {
        if (grow < 32) { wrow = Wq + (size_t)grow * 256; scale = LOG2E; }
        else           { wrow = Wk + (size_t)(grow - 32) * 256; }
      } else {
        wrow = Wv + (size_t)(grow - 64) * 256;
      }
      float4 v = *(const float4*)(wrow + c0 + c4);
      wt[c4 + 0][d] = v.x * scale;
      wt[c4 + 1][d] = v.y * scale;
      wt[c4 + 2][d] = v.z * scale;
      wt[c4 + 3][d] = v.w * scale;
    }
    __syncthreads();

#pragma unroll
    for (int cc = 0; cc < 32; ++cc) {
      float4 xv0 = *(const float4*)&xs[cc][nthr * 4];
      float4 xv1 = *(const float4*)&xs[cc][nthr * 4 + 128];
      float4 wv0 = *(const float4*)&wt[cc][dthr * 8];
      float4 wv1 = *(const float4*)&wt[cc][dthr * 8 + 4];
      float wr[8] = {wv0.x, wv0.y, wv0.z, wv0.w, wv1.x, wv1.y, wv1.z, wv1.w};
      float xr[8] = {xv0.x, xv0.y, xv0.z, xv0.w, xv1.x, xv1.y, xv1.z, xv1.w};
#pragma unroll
      for (int dd = 0; dd < 8; ++dd)
#pragma unroll
        for (int nn = 0; nn < 8; ++nn)
          acc[dd][nn] = fmaf(wr[dd], xr[nn], acc[dd][nn]);
    }
  }

  // ---- epilogue ----
  if (dt == 0 && dthr < 4) {
#pragma unroll
    for (int dd = 0; dd < 8; ++dd) {
      int grow = dthr * 8 + dd;
      ushort* dst = qo + ((size_t)b * 32 + grow) * 4096;
      float bias = bq[grow] * LOG2E;
      ushort4 w0, w1;
      w0.x = f2bf(acc[dd][0] + bias); w0.y = f2bf(acc[dd][1] + bias);
      w0.z = f2bf(acc[dd][2] + bias); w0.w = f2bf(acc[dd][3] + bias);
      w1.x = f2bf(acc[dd][4] + bias); w1.y = f2bf(acc[dd][5] + bias);
      w1.z = f2bf(acc[dd][6] + bias); w1.w = f2bf(acc[dd][7] + bias);
      *(ushort4*)(dst + n0 + nthr * 4) = w0;
      *(ushort4*)(dst + n0 + nthr * 4 + 128) = w1;
    }
  } else if (dt == 0) {
    const int dkbase = (dthr - 4) * 8;
    const int j = dkbase >> 4;
    const int khi = (dkbase >> 3) & 1;
    float bias[8];
#pragma unroll
    for (int dd = 0; dd < 8; ++dd) bias[dd] = bk[dkbase + dd];
    const size_t kzb = (size_t)b * 131072;
#pragma unroll
    for (int nn = 0; nn < 8; ++nn) {
      int n = n0 + nthr * 4 + (nn & 3) + (nn >> 2) * 128;
      int kk = n & 31, T = n >> 5;
      size_t base = kzb + (size_t)T * 1024 + j * 512 + khi * 256 + kk * 8;
      ushort4 a, bb;
      a.x = f2bf(acc[0][nn] + bias[0]); a.y = f2bf(acc[1][nn] + bias[1]);
      a.z = f2bf(acc[2][nn] + bias[2]); a.w = f2bf(acc[3][nn] + bias[3]);
      bb.x = f2bf(acc[4][nn] + bias[4]); bb.y = f2bf(acc[5][nn] + bias[5]);
      bb.z = f2bf(acc[6][nn] + bias[6]); bb.w = f2bf(acc[7][nn] + bias[7]);
      *(ushort4*)(ko + base) = a;
      *(ushort4*)(ko + base + 4) = bb;
    }
  } else {
    const int cbase = (dt - 1) * 64 + dthr * 8;
    const int kk4 = (nthr * 4) & 31;
    const int T0 = (n0 + nthr * 4) >> 5;
    const int vhi = (kk4 >> 3) & 1;
    const int i4 = kk4 & 7;
    const size_t vzb = (size_t)b * 1048576;
#pragma unroll
    for (int dd = 0; dd < 8; ++dd) {
      int c = cbase + dd;
      float bias = bv[c];
      int jj = (c >> 5) * 2 + (kk4 >> 4);
      int l = c & 31;
      size_t off0 = vzb + (size_t)T0 * 8192 + (size_t)jj * 512 + vhi * 256 + l * 8 + i4;
      ushort4 w0, w1;
      w0.x = f2bf(acc[dd][0] + bias); w0.y = f2bf(acc[dd][1] + bias);
      w0.z = f2bf(acc[dd][2] + bias); w0.w = f2bf(acc[dd][3] + bias);
      w1.x = f2bf(acc[dd][4] + bias); w1.y = f2bf(acc[dd][5] + bias);
      w1.z = f2bf(acc[dd][6] + bias); w1.w = f2bf(acc[dd][7] + bias);
      *(ushort4*)(vo + off0) = w0;
      *(ushort4*)(vo + off0 + 4 * 8192) = w1;
    }
  }
}

// ---------------------------------------------------------------------------
// online softmax + P packing for one 32-m set. All acc indices compile-time
// (rule #20).
// ---------------------------------------------------------------------------
static __device__ __forceinline__ void softmax_pack(
    f32x16& s, float& mrun, float& lsum, f32x16 (&acc)[8],
    bf16x8& pb0o, bf16x8& pb1o)
{
  float pm = s[0];
#pragma unroll
  for (int r = 1; r < 16; ++r) pm = fmaxf(pm, s[r]);
  pm = fmaxf(pm, __shfl_xor(pm, 32));

  if (!__all(pm <= mrun + 8.0f)) {              // defer-max (T13), log2 domain
    float mnew = fmaxf(mrun, pm);
    float a = EXP2(mrun - mnew);
    mrun = mnew;
    lsum *= a;
#pragma unroll
    for (int t8 = 0; t8 < 8; ++t8)
#pragma unroll
      for (int r = 0; r < 16; ++r) acc[t8][r] *= a;
  }

  float p[16];
  float ps = 0.f;
#pragma unroll
  for (int r = 0; r < 16; ++r) { p[r] = EXP2(s[r] - mrun); ps += p[r]; }
  ps += __shfl_xor(ps, 32);
  lsum += ps;

  uint pw[8];
#pragma unroll
  for (int j = 0; j < 8; ++j) pw[j] = cvtpk_bf16(p[2 * j], p[2 * j + 1]);
  plswap(pw[0], pw[2]); plswap(pw[1], pw[3]);
  plswap(pw[4], pw[6]); plswap(pw[5], pw[7]);
  union { uint u[4]; bf16x8 v; } pb0u, pb1u;
  pb0u.u[0] = pw[0]; pb0u.u[1] = pw[1]; pb0u.u[2] = pw[2]; pb0u.u[3] = pw[3];
  pb1u.u[0] = pw[4]; pb1u.u[1] = pw[5]; pb1u.u[2] = pw[6]; pb1u.u[3] = pw[7];
  pb0o = pb0u.v; pb1o = pb1u.v;
}

// ---------------------------------------------------------------------------
// Kernel 2: fused flash attention + residual.
// Block = 256 thr (4 waves) owning 128 m; iterates ALL 4096 keys (no merge).
// K (2KB) + V (16KB) per 32-key tile staged into double-buffered LDS
// (reg-staged, T14 split; fragment-major layout => LDS is a linear copy,
// dense conflict-free b128 traffic). Each V byte feeds 4 waves from LDS
// (128 B/cy) instead of 4 L2 streams (~27 B/cy measured R3).
// R4 lesson: 2 acc sets/wave = 256 AGPRs = guaranteed spill; reuse must go
// through LDS, not registers.
// ---------------------------------------------------------------------------
__global__ __launch_bounds__(256, 1) void attn_fused(
    const ushort* __restrict__ qs, const ushort* __restrict__ kz,
    const ushort* __restrict__ vz, const float* __restrict__ x,
    const float* __restrict__ gamma, float* __restrict__ out)
{
  __shared__ __align__(16) ushort kbuf[2][1024];   //  4 KB
  __shared__ __align__(16) ushort vbuf[2][8192];   // 32 KB

  const int wg = blockIdx.x;                      // 0..255
  const int swz = (wg & 7) * 32 + (wg >> 3);      // one batch per XCD
  const int b = swz >> 5, mt = swz & 31;
  const int tid = threadIdx.x;
  const int w = tid >> 6, lane = tid & 63;
  const int l31 = lane & 31, hi = lane >> 5;
  const int m = mt * 128 + w * 32 + l31;

  // resident Q B-frags: qf[j] holds q[j*16 + 8*hi + i][m]
  const ushort* qcol = qs + (size_t)b * 131072 + m;
  bf16x8 qf0, qf1;
  {
    union { ushort s[8]; bf16x8 v; } u0, u1;
#pragma unroll
    for (int i = 0; i < 8; ++i) {
      u0.s[i] = qcol[(size_t)(8 * hi + i) * 4096];
      u1.s[i] = qcol[(size_t)(16 + 8 * hi + i) * 4096];
    }
    qf0 = u0.v; qf1 = u1.v;
  }

  const ushort* kb = kz + (size_t)b * 131072;
  const ushort* vb = vz + (size_t)b * 1048576;

  f32x16 acc[8];
#pragma unroll
  for (int t8 = 0; t8 < 8; ++t8)
#pragma unroll
    for (int r = 0; r < 16; ++r) acc[t8][r] = 0.f;

  float mrun = -1e30f, lsum = 0.f;

  // staged regs for tile t+1/t+2: V 4x16B per thread, K 1x16B (tid<128)
  uint4 vst[4];
  uint4 kst;

  auto LOADR = [&](int t) {
#pragma unroll
    for (int i = 0; i < 4; ++i)
      vst[i] = *(const uint4*)(vb + (size_t)t * 8192 + (tid + i * 256) * 8);
    if (tid < 128) kst = *(const uint4*)(kb + (size_t)t * 1024 + tid * 8);
  };
  auto WRITE = [&](int bi) {
#pragma unroll
    for (int i = 0; i < 4; ++i)
      *(uint4*)&vbuf[bi][(tid + i * 256) * 8] = vst[i];
    if (tid < 128) *(uint4*)&kbuf[bi][tid * 8] = kst;
  };

  LOADR(0);
  WRITE(0);
  __syncthreads();
  LOADR(1);

  for (int t = 0; t < 128; ++t) {
    const int cur = t & 1;

    // --- QK^T (swapped): S^T[key][m], scores in log2 domain ---
    bf16x8 ka0 = *(const bf16x8*)&kbuf[cur][lane * 8];
    bf16x8 ka1 = *(const bf16x8*)&kbuf[cur][512 + lane * 8];
    f32x16 s;
#pragma unroll
    for (int r = 0; r < 16; ++r) s[r] = 0.f;
    s = __builtin_amdgcn_mfma_f32_32x32x16_bf16(ka0, qf0, s, 0, 0, 0);
    s = __builtin_amdgcn_mfma_f32_32x32x16_bf16(ka1, qf1, s, 0, 0, 0);

    bf16x8 pb0, pb1;
    softmax_pack(s, mrun, lsum, acc, pb0, pb1);

    // --- PV: O^T[c][m] += V[c][keys] * P^T[keys][m], V frags from LDS ---
#pragma unroll
    for (int t8 = 0; t8 < 8; ++t8) {
      bf16x8 va0 = *(const bf16x8*)&vbuf[cur][(t8 * 2 + 0) * 512 + lane * 8];
      bf16x8 va1 = *(const bf16x8*)&vbuf[cur][(t8 * 2 + 1) * 512 + lane * 8];
      acc[t8] = __builtin_amdgcn_mfma_f32_32x32x16_bf16(va0, pb0, acc[t8], 0, 0, 0);
      acc[t8] = __builtin_amdgcn_mfma_f32_32x32x16_bf16(va1, pb1, acc[t8], 0, 0, 0);
    }

    __syncthreads();                    // all waves done reading buf[cur]
    if (t < 127) {
      WRITE(cur ^ 1);                   // tile t+1 (regs loaded at t-1)
      __syncthreads();                  // writes visible before next compute
      if (t < 126) LOADR(t + 2);        // latency hidden under compute(t+1)
    }
  }

  // ---- epilogue: normalize, gamma*out + x (no merge — full key range) ----
  const float inv = 1.0f / lsum;
  const float g = gamma[0];
  const float* xc = x + (size_t)b * 256 * 4096 + m;
  float* oc = out + (size_t)b * 256 * 4096 + m;
#pragma unroll
  for (int t8 = 0; t8 < 8; ++t8) {
#pragma unroll
    for (int r = 0; r < 16; ++r) {
      int c = t8 * 32 + (r & 3) + 8 * (r >> 2) + 4 * hi;
      oc[(size_t)c * 4096] = g * (acc[t8][r] * inv) + xc[(size_t)c * 4096];
    }
  }
}

extern "C" void kernel_launch(void* const* d_in, const int* in_sizes, int n_in,
                              void* d_out, int out_size, void* d_ws, size_t ws_size,
                              hipStream_t stream) {
  const float* x  = (const float*)d_in[0];
  const float* Wq = (const float*)d_in[1];
  const float* bq = (const float*)d_in[2];
  const float* Wk = (const float*)d_in[3];
  const float* bk = (const float*)d_in[4];
  const float* Wv = (const float*)d_in[5];
  const float* bv = (const float*)d_in[6];
  const float* gm = (const float*)d_in[7];
  float* out = (float*)d_out;

  ushort* qs = (ushort*)d_ws;
  ushort* kzp = qs + (size_t)8 * 131072;
  ushort* vzp = kzp + (size_t)8 * 131072;

  proj_qkv<<<dim3(16, 8, 5), 256, 0, stream>>>(x, Wq, bq, Wk, bk, Wv, bv, qs, kzp, vzp);
  attn_fused<<<dim3(256), 256, 0, stream>>>(qs, kzp, vzp, x, gm, out);
}

// Round 6
// 280.534 us; speedup vs baseline: 1.4685x; 1.0850x over previous
//
#include <hip/hip_runtime.h>
#include <cstdint>

typedef __bf16 bf16x8 __attribute__((ext_vector_type(8)));
typedef float f32x16 __attribute__((ext_vector_type(16)));

#define LOG2E 1.44269504088896340736f

static __device__ __forceinline__ ushort f2bf(float f) {
  uint u = __builtin_bit_cast(uint, f);
  u = u + 0x7FFFu + ((u >> 16) & 1u);   // RNE
  return (ushort)(u >> 16);
}

static __device__ __forceinline__ uint cvtpk_bf16(float lo, float hi) {
  uint r;
  asm("v_cvt_pk_bf16_f32 %0, %1, %2" : "=v"(r) : "v"(lo), "v"(hi));
  return r;
}

static __device__ __forceinline__ void plswap(uint& a, uint& b) {
  asm("v_permlane32_swap_b32 %0, %1" : "+v"(a), "+v"(b));
}

#if __has_builtin(__builtin_amdgcn_exp2f)
#define EXP2(x) __builtin_amdgcn_exp2f(x)
#else
#define EXP2(x) exp2f(x)
#endif

// ---------------------------------------------------------------------------
// Workspace layouts (all bf16 as ushort):
//   qs : [b][32 d][4096 m]                      (2 MB)
//   kz : [b][128 T][frag j(2)][lane(64)][i(8)]  (2 MB)  K-tile fragment-major
//   vz : [b][128 T][frag j(16)][lane(64)][i(8)] (16 MB) V-tile fragment-major
// A-frag convention (verified R1): lane holds A[row=l31][k=8*hi+i].
// ---------------------------------------------------------------------------

__global__ __launch_bounds__(256, 2) void proj_qkv(
    const float* __restrict__ x,
    const float* __restrict__ Wq, const float* __restrict__ bq,
    const float* __restrict__ Wk, const float* __restrict__ bk,
    const float* __restrict__ Wv, const float* __restrict__ bv,
    ushort* __restrict__ qo, ushort* __restrict__ ko, ushort* __restrict__ vo)
{
  __shared__ float xs[32][256];   // [c][n]
  __shared__ float wt[32][64];    // [c][d] (transposed W chunk)

  const int tid = threadIdx.x;
  const int nt = blockIdx.x, b = blockIdx.y, dt = blockIdx.z;
  const int n0 = nt * 256;
  const int nthr = tid & 31;
  const int dthr = tid >> 5;

  float acc[8][8];
#pragma unroll
  for (int i = 0; i < 8; ++i)
#pragma unroll
    for (int j = 0; j < 8; ++j) acc[i][j] = 0.f;

  const float* xb = x + (size_t)b * 256 * 4096;

  for (int kc = 0; kc < 8; ++kc) {
    const int c0 = kc * 32;
    __syncthreads();
#pragma unroll
    for (int r = 0; r < 8; ++r) {
      int id = r * 256 + tid;
      int c = id >> 6, pos = (id & 63) * 4;
      float4 v = *(const float4*)(xb + (size_t)(c0 + c) * 4096 + n0 + pos);
      *(float4*)&xs[c][pos] = v;
    }
#pragma unroll
    for (int r = 0; r < 2; ++r) {
      int id = r * 256 + tid;
      int d = id >> 3, c4 = (id & 7) * 4;
      int grow = dt * 64 + d;
      const float* wrow;
      float scale = 1.f;
      if (dt == 0) {
        if (grow < 32) { wrow = Wq + (size_t)grow * 256; scale = LOG2E; }
        else           { wrow = Wk + (size_t)(grow - 32) * 256; }
      } else {
        wrow = Wv + (size_t)(grow - 64) * 256;
      }
      float4 v = *(const float4*)(wrow + c0 + c4);
      wt[c4 + 0][d] = v.x * scale;
      wt[c4 + 1][d] = v.y * scale;
      wt[c4 + 2][d] = v.z * scale;
      wt[c4 + 3][d] = v.w * scale;
    }
    __syncthreads();

#pragma unroll
    for (int cc = 0; cc < 32; ++cc) {
      float4 xv0 = *(const float4*)&xs[cc][nthr * 4];
      float4 xv1 = *(const float4*)&xs[cc][nthr * 4 + 128];
      float4 wv0 = *(const float4*)&wt[cc][dthr * 8];
      float4 wv1 = *(const float4*)&wt[cc][dthr * 8 + 4];
      float wr[8] = {wv0.x, wv0.y, wv0.z, wv0.w, wv1.x, wv1.y, wv1.z, wv1.w};
      float xr[8] = {xv0.x, xv0.y, xv0.z, xv0.w, xv1.x, xv1.y, xv1.z, xv1.w};
#pragma unroll
      for (int dd = 0; dd < 8; ++dd)
#pragma unroll
        for (int nn = 0; nn < 8; ++nn)
          acc[dd][nn] = fmaf(wr[dd], xr[nn], acc[dd][nn]);
    }
  }

  // ---- epilogue ----
  if (dt == 0 && dthr < 4) {
#pragma unroll
    for (int dd = 0; dd < 8; ++dd) {
      int grow = dthr * 8 + dd;
      ushort* dst = qo + ((size_t)b * 32 + grow) * 4096;
      float bias = bq[grow] * LOG2E;
      ushort4 w0, w1;
      w0.x = f2bf(acc[dd][0] + bias); w0.y = f2bf(acc[dd][1] + bias);
      w0.z = f2bf(acc[dd][2] + bias); w0.w = f2bf(acc[dd][3] + bias);
      w1.x = f2bf(acc[dd][4] + bias); w1.y = f2bf(acc[dd][5] + bias);
      w1.z = f2bf(acc[dd][6] + bias); w1.w = f2bf(acc[dd][7] + bias);
      *(ushort4*)(dst + n0 + nthr * 4) = w0;
      *(ushort4*)(dst + n0 + nthr * 4 + 128) = w1;
    }
  } else if (dt == 0) {
    const int dkbase = (dthr - 4) * 8;
    const int j = dkbase >> 4;
    const int khi = (dkbase >> 3) & 1;
    float bias[8];
#pragma unroll
    for (int dd = 0; dd < 8; ++dd) bias[dd] = bk[dkbase + dd];
    const size_t kzb = (size_t)b * 131072;
#pragma unroll
    for (int nn = 0; nn < 8; ++nn) {
      int n = n0 + nthr * 4 + (nn & 3) + (nn >> 2) * 128;
      int kk = n & 31, T = n >> 5;
      size_t base = kzb + (size_t)T * 1024 + j * 512 + khi * 256 + kk * 8;
      ushort4 a, bb;
      a.x = f2bf(acc[0][nn] + bias[0]); a.y = f2bf(acc[1][nn] + bias[1]);
      a.z = f2bf(acc[2][nn] + bias[2]); a.w = f2bf(acc[3][nn] + bias[3]);
      bb.x = f2bf(acc[4][nn] + bias[4]); bb.y = f2bf(acc[5][nn] + bias[5]);
      bb.z = f2bf(acc[6][nn] + bias[6]); bb.w = f2bf(acc[7][nn] + bias[7]);
      *(ushort4*)(ko + base) = a;
      *(ushort4*)(ko + base + 4) = bb;
    }
  } else {
    const int cbase = (dt - 1) * 64 + dthr * 8;
    const int kk4 = (nthr * 4) & 31;
    const int T0 = (n0 + nthr * 4) >> 5;
    const int vhi = (kk4 >> 3) & 1;
    const int i4 = kk4 & 7;
    const size_t vzb = (size_t)b * 1048576;
#pragma unroll
    for (int dd = 0; dd < 8; ++dd) {
      int c = cbase + dd;
      float bias = bv[c];
      int jj = (c >> 5) * 2 + (kk4 >> 4);
      int l = c & 31;
      size_t off0 = vzb + (size_t)T0 * 8192 + (size_t)jj * 512 + vhi * 256 + l * 8 + i4;
      ushort4 w0, w1;
      w0.x = f2bf(acc[dd][0] + bias); w0.y = f2bf(acc[dd][1] + bias);
      w0.z = f2bf(acc[dd][2] + bias); w0.w = f2bf(acc[dd][3] + bias);
      w1.x = f2bf(acc[dd][4] + bias); w1.y = f2bf(acc[dd][5] + bias);
      w1.z = f2bf(acc[dd][6] + bias); w1.w = f2bf(acc[dd][7] + bias);
      *(ushort4*)(vo + off0) = w0;
      *(ushort4*)(vo + off0 + 4 * 8192) = w1;
    }
  }
}

// ---------------------------------------------------------------------------
// online softmax + P packing, 4-tile (c-split) accumulator variant.
// All acc indices compile-time (rule #20).
// ---------------------------------------------------------------------------
static __device__ __forceinline__ void softmax_pack4(
    f32x16& s, float& mrun, float& lsum, f32x16 (&acc)[4],
    bf16x8& pb0o, bf16x8& pb1o)
{
  float pm = s[0];
#pragma unroll
  for (int r = 1; r < 16; ++r) pm = fmaxf(pm, s[r]);
  pm = fmaxf(pm, __shfl_xor(pm, 32));

  if (!__all(pm <= mrun + 8.0f)) {              // defer-max (T13), log2 domain
    float mnew = fmaxf(mrun, pm);
    float a = EXP2(mrun - mnew);
    mrun = mnew;
    lsum *= a;
#pragma unroll
    for (int t8 = 0; t8 < 4; ++t8)
#pragma unroll
      for (int r = 0; r < 16; ++r) acc[t8][r] *= a;
  }

  float p[16];
  float ps = 0.f;
#pragma unroll
  for (int r = 0; r < 16; ++r) { p[r] = EXP2(s[r] - mrun); ps += p[r]; }
  ps += __shfl_xor(ps, 32);
  lsum += ps;

  uint pw[8];
#pragma unroll
  for (int j = 0; j < 8; ++j) pw[j] = cvtpk_bf16(p[2 * j], p[2 * j + 1]);
  plswap(pw[0], pw[2]); plswap(pw[1], pw[3]);
  plswap(pw[4], pw[6]); plswap(pw[5], pw[7]);
  union { uint u[4]; bf16x8 v; } pb0u, pb1u;
  pb0u.u[0] = pw[0]; pb0u.u[1] = pw[1]; pb0u.u[2] = pw[2]; pb0u.u[3] = pw[3];
  pb1u.u[0] = pw[4]; pb1u.u[1] = pw[5]; pb1u.u[2] = pw[6]; pb1u.u[3] = pw[7];
  pb0o = pb0u.v; pb1o = pb1u.v;
}

// ---------------------------------------------------------------------------
// Kernel 2: fused flash attention + residual.
// Block = 512 thr = 8 waves = (kh key-half) x (ch c-half) x (mg m-group).
// Each wave: 64 m (2 msets, dual online-softmax) x 128 c (c-half) ->
// acc = 2x4x16 = 128 regs (R4 lesson: total acc must stay <=128).
// Two LDS streams (kh0: tiles 0..63, kh1: 64..127), double-buffered;
// each staged V byte feeds 4 waves, per-wave LDS read 10KB/tile (vs 18).
// Grid 256 = 1 block/CU but 2 waves/SIMD (R5 lesson: 1 wave/SIMD
// serializes). kh-partner merge via two 64KB passes overlaying staging LDS.
// ---------------------------------------------------------------------------
__global__ __launch_bounds__(512, 1) void attn_fused(
    const ushort* __restrict__ qs, const ushort* __restrict__ kz,
    const ushort* __restrict__ vz, const float* __restrict__ x,
    const float* __restrict__ gamma, float* __restrict__ out)
{
  __shared__ __align__(16) union SMem {
    struct { ushort k[2][2][1024]; ushort v[2][2][8192]; } st;  // 72 KB
    float xch[4][4][16][64];                                    // 64 KB overlay
  } sm;
  __shared__ float sml[8][2][2][64];                            // 8 KB

  const int wg = blockIdx.x;                      // 0..255
  const int swz = (wg & 7) * 32 + (wg >> 3);      // one batch per XCD
  const int b = swz >> 5, mt = swz & 31;
  const int tid = threadIdx.x;
  const int wv = tid >> 6, lane = tid & 63;
  const int l31 = lane & 31, hi = lane >> 5;
  const int kh = wv >> 2, ch = (wv >> 1) & 1, mg = wv & 1;
  const int m0 = mt * 128 + mg * 64 + l31;        // mset0 column (mset1 = +32)

  // resident Q B-frags (2 msets x 2 k-frags)
  const ushort* qc0 = qs + (size_t)b * 131072 + m0;
  bf16x8 qf0, qf1, qf2, qf3;
  {
    union { ushort s[8]; bf16x8 v; } u0, u1, u2, u3;
#pragma unroll
    for (int i = 0; i < 8; ++i) {
      u0.s[i] = qc0[(size_t)(8 * hi + i) * 4096];
      u1.s[i] = qc0[(size_t)(16 + 8 * hi + i) * 4096];
      u2.s[i] = qc0[32 + (size_t)(8 * hi + i) * 4096];
      u3.s[i] = qc0[32 + (size_t)(16 + 8 * hi + i) * 4096];
    }
    qf0 = u0.v; qf1 = u1.v; qf2 = u2.v; qf3 = u3.v;
  }

  // staging: thread-half str stages stream str (tiles str*64 + t)
  const int str = tid >> 8, th = tid & 255;
  const ushort* kb = kz + (size_t)b * 131072 + (size_t)str * 64 * 1024;
  const ushort* vb = vz + (size_t)b * 1048576 + (size_t)str * 64 * 8192;

  f32x16 acc0[4], acc1[4];
#pragma unroll
  for (int t8 = 0; t8 < 4; ++t8)
#pragma unroll
    for (int r = 0; r < 16; ++r) { acc0[t8][r] = 0.f; acc1[t8][r] = 0.f; }

  float mrun0 = -1e30f, lsum0 = 0.f;
  float mrun1 = -1e30f, lsum1 = 0.f;

  uint4 vst[4];
  uint4 kst;

  auto LOADR = [&](int t) {
#pragma unroll
    for (int i = 0; i < 4; ++i)
      vst[i] = *(const uint4*)(vb + (size_t)t * 8192 + (th + i * 256) * 8);
    if (th < 128) kst = *(const uint4*)(kb + (size_t)t * 1024 + th * 8);
  };
  auto WRITE = [&](int bi) {
#pragma unroll
    for (int i = 0; i < 4; ++i)
      *(uint4*)&sm.st.v[str][bi][(th + i * 256) * 8] = vst[i];
    if (th < 128) *(uint4*)&sm.st.k[str][bi][th * 8] = kst;
  };

  LOADR(0);
  WRITE(0);
  __syncthreads();
  LOADR(1);

  for (int t = 0; t < 64; ++t) {
    const int cur = t & 1;

    // --- QK^T (swapped): S^T[key][m], both msets, log2 domain ---
    bf16x8 ka0 = *(const bf16x8*)&sm.st.k[kh][cur][lane * 8];
    bf16x8 ka1 = *(const bf16x8*)&sm.st.k[kh][cur][512 + lane * 8];
    f32x16 s0, s1;
#pragma unroll
    for (int r = 0; r < 16; ++r) { s0[r] = 0.f; s1[r] = 0.f; }
    s0 = __builtin_amdgcn_mfma_f32_32x32x16_bf16(ka0, qf0, s0, 0, 0, 0);
    s0 = __builtin_amdgcn_mfma_f32_32x32x16_bf16(ka1, qf1, s0, 0, 0, 0);
    s1 = __builtin_amdgcn_mfma_f32_32x32x16_bf16(ka0, qf2, s1, 0, 0, 0);
    s1 = __builtin_amdgcn_mfma_f32_32x32x16_bf16(ka1, qf3, s1, 0, 0, 0);

    bf16x8 pA0, pA1, pB0, pB1;
    softmax_pack4(s0, mrun0, lsum0, acc0, pA0, pA1);
    softmax_pack4(s1, mrun1, lsum1, acc1, pB0, pB1);

    // --- PV over this wave's c-half: each V frag feeds both msets ---
#pragma unroll
    for (int t8 = 0; t8 < 4; ++t8) {
      const int ct = ch * 4 + t8;   // ch wave-uniform; addr compile-time shape
      bf16x8 va0 = *(const bf16x8*)&sm.st.v[kh][cur][(ct * 2 + 0) * 512 + lane * 8];
      bf16x8 va1 = *(const bf16x8*)&sm.st.v[kh][cur][(ct * 2 + 1) * 512 + lane * 8];
      acc0[t8] = __builtin_amdgcn_mfma_f32_32x32x16_bf16(va0, pA0, acc0[t8], 0, 0, 0);
      acc1[t8] = __builtin_amdgcn_mfma_f32_32x32x16_bf16(va0, pB0, acc1[t8], 0, 0, 0);
      acc0[t8] = __builtin_amdgcn_mfma_f32_32x32x16_bf16(va1, pA1, acc0[t8], 0, 0, 0);
      acc1[t8] = __builtin_amdgcn_mfma_f32_32x32x16_bf16(va1, pB1, acc1[t8], 0, 0, 0);
    }

    __syncthreads();                    // all waves done reading buf[cur]
    if (t < 63) {
      WRITE(cur ^ 1);                   // tile t+1 (regs loaded at t-1)
      __syncthreads();                  // writes visible before next compute
      if (t < 62) LOADR(t + 2);         // latency hidden under compute(t+1)
    }
  }

  // ---- merge kh-partners (wv ^ 4): two passes overlaying staging LDS ----
  sml[wv][0][0][lane] = mrun0; sml[wv][0][1][lane] = lsum0;
  sml[wv][1][0][lane] = mrun1; sml[wv][1][1][lane] = lsum1;
  __syncthreads();
  const int pwv = wv ^ 4;
  const float mo0 = sml[pwv][0][0][lane], lo0 = sml[pwv][0][1][lane];
  const float mo1 = sml[pwv][1][0][lane], lo1 = sml[pwv][1][1][lane];
  const float ms0 = fmaxf(mrun0, mo0);
  const float aw0 = EXP2(mrun0 - ms0);
  const float lt0 = lsum0 * aw0 + lo0 * EXP2(mo0 - ms0);
  const float ms1 = fmaxf(mrun1, mo1);
  const float aw1 = EXP2(mrun1 - ms1);
  const float lt1 = lsum1 * aw1 + lo1 * EXP2(mo1 - ms1);
#pragma unroll
  for (int t8 = 0; t8 < 4; ++t8)
#pragma unroll
    for (int r = 0; r < 16; ++r) { acc0[t8][r] *= aw0; acc1[t8][r] *= aw1; }

  const int slot = wv & 3;             // (ch, mg) pair id
  const float g = gamma[0];
  const float* xc = x + (size_t)b * 256 * 4096 + m0;
  float* oc = out + (size_t)b * 256 * 4096 + m0;

  // pass A: kh1 ships mset0; kh0 merges + writes out mset0 (its c-half)
  if (kh == 1) {
#pragma unroll
    for (int q = 0; q < 4; ++q)
#pragma unroll
      for (int r = 0; r < 16; ++r)
        sm.xch[slot][q][r][lane] = acc0[q][r];
  }
  __syncthreads();
  if (kh == 0) {
    const float inv0 = 1.0f / lt0;
#pragma unroll
    for (int q = 0; q < 4; ++q)
#pragma unroll
      for (int r = 0; r < 16; ++r) {
        float val = acc0[q][r] + sm.xch[slot][q][r][lane];
        int c = ch * 128 + q * 32 + (r & 3) + 8 * (r >> 2) + 4 * hi;
        oc[(size_t)c * 4096] = g * (val * inv0) + xc[(size_t)c * 4096];
      }
  }
  __syncthreads();
  // pass B: kh0 ships mset1; kh1 merges + writes out mset1 (m0+32)
  if (kh == 0) {
#pragma unroll
    for (int q = 0; q < 4; ++q)
#pragma unroll
      for (int r = 0; r < 16; ++r)
        sm.xch[slot][q][r][lane] = acc1[q][r];
  }
  __syncthreads();
  if (kh == 1) {
    const float inv1 = 1.0f / lt1;
#pragma unroll
    for (int q = 0; q < 4; ++q)
#pragma unroll
      for (int r = 0; r < 16; ++r) {
        float val = acc1[q][r] + sm.xch[slot][q][r][lane];
        int c = ch * 128 + q * 32 + (r & 3) + 8 * (r >> 2) + 4 * hi;
        oc[32 + (size_t)c * 4096] = g * (val * inv1) + xc[32 + (size_t)c * 4096];
      }
  }
}

extern "C" void kernel_launch(void* const* d_in, const int* in_sizes, int n_in,
                              void* d_out, int out_size, void* d_ws, size_t ws_size,
                              hipStream_t stream) {
  const float* x  = (const float*)d_in[0];
  const float* Wq = (const float*)d_in[1];
  const float* bq = (const float*)d_in[2];
  const float* Wk = (const float*)d_in[3];
  const float* bk = (const float*)d_in[4];
  const float* Wv = (const float*)d_in[5];
  const float* bv = (const float*)d_in[6];
  const float* gm = (const float*)d_in[7];
  float* out = (float*)d_out;

  ushort* qs = (ushort*)d_ws;
  ushort* kzp = qs + (size_t)8 * 131072;
  ushort* vzp = kzp + (size_t)8 * 131072;

  proj_qkv<<<dim3(16, 8, 5), 256, 0, stream>>>(x, Wq, bq, Wk, bk, Wv, bv, qs, kzp, vzp);
  attn_fused<<<dim3(256), 512, 0, stream>>>(qs, kzp, vzp, x, gm, out);
}

// Round 7
// 237.958 us; speedup vs baseline: 1.7312x; 1.1789x over previous
//
#include <hip/hip_runtime.h>
#include <cstdint>

typedef __bf16 bf16x8 __attribute__((ext_vector_type(8)));
typedef float f32x16 __attribute__((ext_vector_type(16)));

#define LOG2E 1.44269504088896340736f

static __device__ __forceinline__ ushort f2bf(float f) {
  uint u = __builtin_bit_cast(uint, f);
  u = u + 0x7FFFu + ((u >> 16) & 1u);   // RNE
  return (ushort)(u >> 16);
}

static __device__ __forceinline__ uint cvtpk_bf16(float lo, float hi) {
  uint r;
  asm("v_cvt_pk_bf16_f32 %0, %1, %2" : "=v"(r) : "v"(lo), "v"(hi));
  return r;
}

static __device__ __forceinline__ void plswap(uint& a, uint& b) {
  asm("v_permlane32_swap_b32 %0, %1" : "+v"(a), "+v"(b));
}

// async global->LDS, 16B per lane; LDS dest must be wave-uniform base
// (HW writes base + lane*16), global src is per-lane.
static __device__ __forceinline__ void gload16(const ushort* g, ushort* l) {
  __builtin_amdgcn_global_load_lds(
      (const __attribute__((address_space(1))) void*)g,
      (__attribute__((address_space(3))) void*)l, 16, 0, 0);
}

#if __has_builtin(__builtin_amdgcn_exp2f)
#define EXP2(x) __builtin_amdgcn_exp2f(x)
#else
#define EXP2(x) exp2f(x)
#endif

// ---------------------------------------------------------------------------
// Workspace layouts (all bf16 as ushort):
//   qs : [b][32 d][4096 m]                      (2 MB)
//   kz : [b][128 T][frag j(2)][lane(64)][i(8)]  (2 MB)  K-tile fragment-major
//   vz : [b][128 T][frag j(16)][lane(64)][i(8)] (16 MB) V-tile fragment-major
// A-frag convention (verified R1): lane holds A[row=l31][k=8*hi+i].
// ---------------------------------------------------------------------------

__global__ __launch_bounds__(256, 2) void proj_qkv(
    const float* __restrict__ x,
    const float* __restrict__ Wq, const float* __restrict__ bq,
    const float* __restrict__ Wk, const float* __restrict__ bk,
    const float* __restrict__ Wv, const float* __restrict__ bv,
    ushort* __restrict__ qo, ushort* __restrict__ ko, ushort* __restrict__ vo)
{
  __shared__ float xs[32][256];   // [c][n]
  __shared__ float wt[32][64];    // [c][d] (transposed W chunk)

  const int tid = threadIdx.x;
  const int nt = blockIdx.x, b = blockIdx.y, dt = blockIdx.z;
  const int n0 = nt * 256;
  const int nthr = tid & 31;
  const int dthr = tid >> 5;

  float acc[8][8];
#pragma unroll
  for (int i = 0; i < 8; ++i)
#pragma unroll
    for (int j = 0; j < 8; ++j) acc[i][j] = 0.f;

  const float* xb = x + (size_t)b * 256 * 4096;

  for (int kc = 0; kc < 8; ++kc) {
    const int c0 = kc * 32;
    __syncthreads();
#pragma unroll
    for (int r = 0; r < 8; ++r) {
      int id = r * 256 + tid;
      int c = id >> 6, pos = (id & 63) * 4;
      float4 v = *(const float4*)(xb + (size_t)(c0 + c) * 4096 + n0 + pos);
      *(float4*)&xs[c][pos] = v;
    }
#pragma unroll
    for (int r = 0; r < 2; ++r) {
      int id = r * 256 + tid;
      int d = id >> 3, c4 = (id & 7) * 4;
      int grow = dt * 64 + d;
      const float* wrow;
      float scale = 1.f;
      if (dt == 0) {
        if (grow < 32) { wrow = Wq + (size_t)grow * 256; scale = LOG2E; }
        else           { wrow = Wk + (size_t)(grow - 32) * 256; }
      } else {
        wrow = Wv + (size_t)(grow - 64) * 256;
      }
      float4 v = *(const float4*)(wrow + c0 + c4);
      wt[c4 + 0][d] = v.x * scale;
      wt[c4 + 1][d] = v.y * scale;
      wt[c4 + 2][d] = v.z * scale;
      wt[c4 + 3][d] = v.w * scale;
    }
    __syncthreads();

#pragma unroll
    for (int cc = 0; cc < 32; ++cc) {
      float4 xv0 = *(const float4*)&xs[cc][nthr * 4];
      float4 xv1 = *(const float4*)&xs[cc][nthr * 4 + 128];
      float4 wv0 = *(const float4*)&wt[cc][dthr * 8];
      float4 wv1 = *(const float4*)&wt[cc][dthr * 8 + 4];
      float wr[8] = {wv0.x, wv0.y, wv0.z, wv0.w, wv1.x, wv1.y, wv1.z, wv1.w};
      float xr[8] = {xv0.x, xv0.y, xv0.z, xv0.w, xv1.x, xv1.y, xv1.z, xv1.w};
#pragma unroll
      for (int dd = 0; dd < 8; ++dd)
#pragma unroll
        for (int nn = 0; nn < 8; ++nn)
          acc[dd][nn] = fmaf(wr[dd], xr[nn], acc[dd][nn]);
    }
  }

  // ---- epilogue ----
  if (dt == 0 && dthr < 4) {
#pragma unroll
    for (int dd = 0; dd < 8; ++dd) {
      int grow = dthr * 8 + dd;
      ushort* dst = qo + ((size_t)b * 32 + grow) * 4096;
      float bias = bq[grow] * LOG2E;
      ushort4 w0, w1;
      w0.x = f2bf(acc[dd][0] + bias); w0.y = f2bf(acc[dd][1] + bias);
      w0.z = f2bf(acc[dd][2] + bias); w0.w = f2bf(acc[dd][3] + bias);
      w1.x = f2bf(acc[dd][4] + bias); w1.y = f2bf(acc[dd][5] + bias);
      w1.z = f2bf(acc[dd][6] + bias); w1.w = f2bf(acc[dd][7] + bias);
      *(ushort4*)(dst + n0 + nthr * 4) = w0;
      *(ushort4*)(dst + n0 + nthr * 4 + 128) = w1;
    }
  } else if (dt == 0) {
    const int dkbase = (dthr - 4) * 8;
    const int j = dkbase >> 4;
    const int khi = (dkbase >> 3) & 1;
    float bias[8];
#pragma unroll
    for (int dd = 0; dd < 8; ++dd) bias[dd] = bk[dkbase + dd];
    const size_t kzb = (size_t)b * 131072;
#pragma unroll
    for (int nn = 0; nn < 8; ++nn) {
      int n = n0 + nthr * 4 + (nn & 3) + (nn >> 2) * 128;
      int kk = n & 31, T = n >> 5;
      size_t base = kzb + (size_t)T * 1024 + j * 512 + khi * 256 + kk * 8;
      ushort4 a, bb;
      a.x = f2bf(acc[0][nn] + bias[0]); a.y = f2bf(acc[1][nn] + bias[1]);
      a.z = f2bf(acc[2][nn] + bias[2]); a.w = f2bf(acc[3][nn] + bias[3]);
      bb.x = f2bf(acc[4][nn] + bias[4]); bb.y = f2bf(acc[5][nn] + bias[5]);
      bb.z = f2bf(acc[6][nn] + bias[6]); bb.w = f2bf(acc[7][nn] + bias[7]);
      *(ushort4*)(ko + base) = a;
      *(ushort4*)(ko + base + 4) = bb;
    }
  } else {
    const int cbase = (dt - 1) * 64 + dthr * 8;
    const int kk4 = (nthr * 4) & 31;
    const int T0 = (n0 + nthr * 4) >> 5;
    const int vhi = (kk4 >> 3) & 1;
    const int i4 = kk4 & 7;
    const size_t vzb = (size_t)b * 1048576;
#pragma unroll
    for (int dd = 0; dd < 8; ++dd) {
      int c = cbase + dd;
      float bias = bv[c];
      int jj = (c >> 5) * 2 + (kk4 >> 4);
      int l = c & 31;
      size_t off0 = vzb + (size_t)T0 * 8192 + (size_t)jj * 512 + vhi * 256 + l * 8 + i4;
      ushort4 w0, w1;
      w0.x = f2bf(acc[dd][0] + bias); w0.y = f2bf(acc[dd][1] + bias);
      w0.z = f2bf(acc[dd][2] + bias); w0.w = f2bf(acc[dd][3] + bias);
      w1.x = f2bf(acc[dd][4] + bias); w1.y = f2bf(acc[dd][5] + bias);
      w1.z = f2bf(acc[dd][6] + bias); w1.w = f2bf(acc[dd][7] + bias);
      *(ushort4*)(vo + off0) = w0;
      *(ushort4*)(vo + off0 + 4 * 8192) = w1;
    }
  }
}

// ---------------------------------------------------------------------------
// online softmax + P packing, acc[4] (c-half) variant.
// All acc indices compile-time (rule #20).
// ---------------------------------------------------------------------------
static __device__ __forceinline__ void softmax_pack4(
    f32x16& s, float& mrun, float& lsum, f32x16 (&acc)[4],
    bf16x8& pb0o, bf16x8& pb1o)
{
  float pm = s[0];
#pragma unroll
  for (int r = 1; r < 16; ++r) pm = fmaxf(pm, s[r]);
  pm = fmaxf(pm, __shfl_xor(pm, 32));

  if (!__all(pm <= mrun + 8.0f)) {              // defer-max (T13), log2 domain
    float mnew = fmaxf(mrun, pm);
    float a = EXP2(mrun - mnew);
    mrun = mnew;
    lsum *= a;
#pragma unroll
    for (int t8 = 0; t8 < 4; ++t8)
#pragma unroll
      for (int r = 0; r < 16; ++r) acc[t8][r] *= a;
  }

  float p[16];
  float ps = 0.f;
#pragma unroll
  for (int r = 0; r < 16; ++r) { p[r] = EXP2(s[r] - mrun); ps += p[r]; }
  ps += __shfl_xor(ps, 32);
  lsum += ps;

  uint pw[8];
#pragma unroll
  for (int j = 0; j < 8; ++j) pw[j] = cvtpk_bf16(p[2 * j], p[2 * j + 1]);
  plswap(pw[0], pw[2]); plswap(pw[1], pw[3]);
  plswap(pw[4], pw[6]); plswap(pw[5], pw[7]);
  union { uint u[4]; bf16x8 v; } pb0u, pb1u;
  pb0u.u[0] = pw[0]; pb0u.u[1] = pw[1]; pb0u.u[2] = pw[2]; pb0u.u[3] = pw[3];
  pb1u.u[0] = pw[4]; pb1u.u[1] = pw[5]; pb1u.u[2] = pw[6]; pb1u.u[3] = pw[7];
  pb0o = pb0u.v; pb1o = pb1u.v;
}

// ---------------------------------------------------------------------------
// Kernel 2: fused flash attention + residual. v7: fully-private per-wave
// streaming. Block = 2 INDEPENDENT waves (no shared data, NO barriers; the
// block exists only to allocate LDS). Wave ch owns m-tile mt x c-half ch
// (acc = 64 regs), walks all 128 key-tiles. Per tile: 10 global_load_lds
// (V-half 8KB + K 2KB, linear dest), double-buffered, synced ONLY by
// counted `s_waitcnt vmcnt(10)` (tile t landed, t+1 in flight). No
// __syncthreads anywhere (it drains vmcnt - the m97 stall). 1024 blocks =
// 4 blocks/CU (40KB LDS) = 8 waves/CU = 2/SIMD, all independent.
// Accepted cost: softmax x2 per m-tile (one per c-half) -> VALU-bound wall.
// ---------------------------------------------------------------------------
__global__ __launch_bounds__(128, 2) void attn_fused(
    const ushort* __restrict__ qs, const ushort* __restrict__ kz,
    const ushort* __restrict__ vz, const float* __restrict__ x,
    const float* __restrict__ gamma, float* __restrict__ out)
{
  __shared__ __align__(16) ushort vbuf[2][2][4096];  // [wave][dbuf][8KB half-tile]
  __shared__ __align__(16) ushort kbuf[2][2][1024];  // [wave][dbuf][2KB K-tile]

  const int wg = blockIdx.x;                      // 0..1023
  const int swz = (wg & 7) * 128 + (wg >> 3);     // one batch per XCD
  const int b = swz >> 7, mt = swz & 127;
  const int tid = threadIdx.x;
  const int ch = tid >> 6, lane = tid & 63;       // ch = wave = c-half
  const int l31 = lane & 31, hi = lane >> 5;
  const int m = mt * 32 + l31;

  // resident Q B-frags: qf[j] holds q[j*16 + 8*hi + i][m]
  const ushort* qcol = qs + (size_t)b * 131072 + m;
  bf16x8 qf0, qf1;
  {
    union { ushort s[8]; bf16x8 v; } u0, u1;
#pragma unroll
    for (int i = 0; i < 8; ++i) {
      u0.s[i] = qcol[(size_t)(8 * hi + i) * 4096];
      u1.s[i] = qcol[(size_t)(16 + 8 * hi + i) * 4096];
    }
    qf0 = u0.v; qf1 = u1.v;
  }

  const ushort* kb = kz + (size_t)b * 131072;
  const ushort* vb = vz + (size_t)b * 1048576;

  f32x16 acc[4];
#pragma unroll
  for (int q = 0; q < 4; ++q)
#pragma unroll
    for (int r = 0; r < 16; ++r) acc[q][r] = 0.f;

  const f32x16 fzero = {};   // loop-invariant zero C operand for QK MFMA

  float mrun = -1e30f, lsum = 0.f;

  // issue 10 async global->LDS per tile: this wave's V c-half (8) + K (2)
  auto ISSUE = [&](int t, int bi) {
#pragma unroll
    for (int i = 0; i < 8; ++i)
      gload16(vb + (size_t)t * 8192 + (size_t)(ch * 8 + i) * 512 + lane * 8,
              &vbuf[ch][bi][i * 512]);
#pragma unroll
    for (int j = 0; j < 2; ++j)
      gload16(kb + (size_t)t * 1024 + (size_t)j * 512 + lane * 8,
              &kbuf[ch][bi][j * 512]);
  };

  auto COMPUTE = [&](int cur) {
    bf16x8 ka0 = *(const bf16x8*)&kbuf[ch][cur][lane * 8];
    bf16x8 ka1 = *(const bf16x8*)&kbuf[ch][cur][512 + lane * 8];
    f32x16 s = __builtin_amdgcn_mfma_f32_32x32x16_bf16(ka0, qf0, fzero, 0, 0, 0);
    s = __builtin_amdgcn_mfma_f32_32x32x16_bf16(ka1, qf1, s, 0, 0, 0);

    bf16x8 pb0, pb1;
    softmax_pack4(s, mrun, lsum, acc, pb0, pb1);

    __builtin_amdgcn_s_setprio(1);               // T5: favor the MFMA cluster
#pragma unroll
    for (int q = 0; q < 4; ++q) {
      bf16x8 va0 = *(const bf16x8*)&vbuf[ch][cur][(q * 2 + 0) * 512 + lane * 8];
      bf16x8 va1 = *(const bf16x8*)&vbuf[ch][cur][(q * 2 + 1) * 512 + lane * 8];
      acc[q] = __builtin_amdgcn_mfma_f32_32x32x16_bf16(va0, pb0, acc[q], 0, 0, 0);
      acc[q] = __builtin_amdgcn_mfma_f32_32x32x16_bf16(va1, pb1, acc[q], 0, 0, 0);
    }
    __builtin_amdgcn_s_setprio(0);
  };

  ISSUE(0, 0);
  ISSUE(1, 1);

  for (int t = 0; t < 127; ++t) {
    // wait: tile t's 10 loads done (t+1's 10 stay in flight). Counted vmcnt,
    // never 0 in the main loop (T4).
    asm volatile("s_waitcnt vmcnt(10)" ::: "memory");
    COMPUTE(t & 1);
    asm volatile("" ::: "memory");   // keep ISSUE below the ds_reads above
    if (t < 126) ISSUE(t + 2, t & 1);
  }
  asm volatile("s_waitcnt vmcnt(0)" ::: "memory");
  COMPUTE(1);

  // ---- epilogue: normalize, gamma*out + x (full key range, no merge) ----
  const float inv = 1.0f / lsum;
  const float g = gamma[0];
  const float* xc = x + (size_t)b * 256 * 4096 + m;
  float* oc = out + (size_t)b * 256 * 4096 + m;
#pragma unroll
  for (int q = 0; q < 4; ++q) {
#pragma unroll
    for (int r = 0; r < 16; ++r) {
      int c = ch * 128 + q * 32 + (r & 3) + 8 * (r >> 2) + 4 * hi;
      oc[(size_t)c * 4096] = g * (acc[q][r] * inv) + xc[(size_t)c * 4096];
    }
  }
}

extern "C" void kernel_launch(void* const* d_in, const int* in_sizes, int n_in,
                              void* d_out, int out_size, void* d_ws, size_t ws_size,
                              hipStream_t stream) {
  const float* x  = (const float*)d_in[0];
  const float* Wq = (const float*)d_in[1];
  const float* bq = (const float*)d_in[2];
  const float* Wk = (const float*)d_in[3];
  const float* bk = (const float*)d_in[4];
  const float* Wv = (const float*)d_in[5];
  const float* bv = (const float*)d_in[6];
  const float* gm = (const float*)d_in[7];
  float* out = (float*)d_out;

  ushort* qs = (ushort*)d_ws;
  ushort* kzp = qs + (size_t)8 * 131072;
  ushort* vzp = kzp + (size_t)8 * 131072;

  proj_qkv<<<dim3(16, 8, 5), 256, 0, stream>>>(x, Wq, bq, Wk, bk, Wv, bv, qs, kzp, vzp);
  attn_fused<<<dim3(1024), 128, 0, stream>>>(qs, kzp, vzp, x, gm, out);
}

// Round 8
// 228.756 us; speedup vs baseline: 1.8009x; 1.0402x over previous
//
#include <hip/hip_runtime.h>
#include <cstdint>

typedef __bf16 bf16x8 __attribute__((ext_vector_type(8)));
typedef float f32x16 __attribute__((ext_vector_type(16)));

#define LOG2E 1.44269504088896340736f

static __device__ __forceinline__ ushort f2bf(float f) {
  uint u = __builtin_bit_cast(uint, f);
  u = u + 0x7FFFu + ((u >> 16) & 1u);   // RNE
  return (ushort)(u >> 16);
}

static __device__ __forceinline__ uint cvtpk_bf16(float lo, float hi) {
  uint r;
  asm("v_cvt_pk_bf16_f32 %0, %1, %2" : "=v"(r) : "v"(lo), "v"(hi));
  return r;
}

static __device__ __forceinline__ void plswap(uint& a, uint& b) {
  asm("v_permlane32_swap_b32 %0, %1" : "+v"(a), "+v"(b));
}

// async global->LDS, 16B per lane; LDS dest wave-uniform base + lane*16.
static __device__ __forceinline__ void gload16(const ushort* g, ushort* l) {
  __builtin_amdgcn_global_load_lds(
      (const __attribute__((address_space(1))) void*)g,
      (__attribute__((address_space(3))) void*)l, 16, 0, 0);
}

#if __has_builtin(__builtin_amdgcn_exp2f)
#define EXP2(x) __builtin_amdgcn_exp2f(x)
#else
#define EXP2(x) exp2f(x)
#endif

// ---------------------------------------------------------------------------
// Workspace layouts (all bf16 as ushort):
//   qs : [b][32 d][4096 m]                      (2 MB)
//   kz : [b][128 T][frag j(2)][lane(64)][i(8)]  (2 MB)  K-tile fragment-major
//   vz : [b][128 T][frag j(16)][lane(64)][i(8)] (16 MB) V-tile fragment-major
// A-frag convention (verified R1): lane holds A[row=l31][k=8*hi+i].
// ---------------------------------------------------------------------------

__global__ __launch_bounds__(256, 2) void proj_qkv(
    const float* __restrict__ x,
    const float* __restrict__ Wq, const float* __restrict__ bq,
    const float* __restrict__ Wk, const float* __restrict__ bk,
    const float* __restrict__ Wv, const float* __restrict__ bv,
    ushort* __restrict__ qo, ushort* __restrict__ ko, ushort* __restrict__ vo)
{
  __shared__ float xs[32][256];   // [c][n]
  __shared__ float wt[32][64];    // [c][d] (transposed W chunk)

  const int tid = threadIdx.x;
  const int nt = blockIdx.x, b = blockIdx.y, dt = blockIdx.z;
  const int n0 = nt * 256;
  const int nthr = tid & 31;
  const int dthr = tid >> 5;

  float acc[8][8];
#pragma unroll
  for (int i = 0; i < 8; ++i)
#pragma unroll
    for (int j = 0; j < 8; ++j) acc[i][j] = 0.f;

  const float* xb = x + (size_t)b * 256 * 4096;

  for (int kc = 0; kc < 8; ++kc) {
    const int c0 = kc * 32;
    __syncthreads();
#pragma unroll
    for (int r = 0; r < 8; ++r) {
      int id = r * 256 + tid;
      int c = id >> 6, pos = (id & 63) * 4;
      float4 v = *(const float4*)(xb + (size_t)(c0 + c) * 4096 + n0 + pos);
      *(float4*)&xs[c][pos] = v;
    }
#pragma unroll
    for (int r = 0; r < 2; ++r) {
      int id = r * 256 + tid;
      int d = id >> 3, c4 = (id & 7) * 4;
      int grow = dt * 64 + d;
      const float* wrow;
      float scale = 1.f;
      if (dt == 0) {
        if (grow < 32) { wrow = Wq + (size_t)grow * 256; scale = LOG2E; }
        else           { wrow = Wk + (size_t)(grow - 32) * 256; }
      } else {
        wrow = Wv + (size_t)(grow - 64) * 256;
      }
      float4 v = *(const float4*)(wrow + c0 + c4);
      wt[c4 + 0][d] = v.x * scale;
      wt[c4 + 1][d] = v.y * scale;
      wt[c4 + 2][d] = v.z * scale;
      wt[c4 + 3][d] = v.w * scale;
    }
    __syncthreads();

#pragma unroll
    for (int cc = 0; cc < 32; ++cc) {
      float4 xv0 = *(const float4*)&xs[cc][nthr * 4];
      float4 xv1 = *(const float4*)&xs[cc][nthr * 4 + 128];
      float4 wv0 = *(const float4*)&wt[cc][dthr * 8];
      float4 wv1 = *(const float4*)&wt[cc][dthr * 8 + 4];
      float wr[8] = {wv0.x, wv0.y, wv0.z, wv0.w, wv1.x, wv1.y, wv1.z, wv1.w};
      float xr[8] = {xv0.x, xv0.y, xv0.z, xv0.w, xv1.x, xv1.y, xv1.z, xv1.w};
#pragma unroll
      for (int dd = 0; dd < 8; ++dd)
#pragma unroll
        for (int nn = 0; nn < 8; ++nn)
          acc[dd][nn] = fmaf(wr[dd], xr[nn], acc[dd][nn]);
    }
  }

  // ---- epilogue ----
  if (dt == 0 && dthr < 4) {
#pragma unroll
    for (int dd = 0; dd < 8; ++dd) {
      int grow = dthr * 8 + dd;
      ushort* dst = qo + ((size_t)b * 32 + grow) * 4096;
      float bias = bq[grow] * LOG2E;
      ushort4 w0, w1;
      w0.x = f2bf(acc[dd][0] + bias); w0.y = f2bf(acc[dd][1] + bias);
      w0.z = f2bf(acc[dd][2] + bias); w0.w = f2bf(acc[dd][3] + bias);
      w1.x = f2bf(acc[dd][4] + bias); w1.y = f2bf(acc[dd][5] + bias);
      w1.z = f2bf(acc[dd][6] + bias); w1.w = f2bf(acc[dd][7] + bias);
      *(ushort4*)(dst + n0 + nthr * 4) = w0;
      *(ushort4*)(dst + n0 + nthr * 4 + 128) = w1;
    }
  } else if (dt == 0) {
    const int dkbase = (dthr - 4) * 8;
    const int j = dkbase >> 4;
    const int khi = (dkbase >> 3) & 1;
    float bias[8];
#pragma unroll
    for (int dd = 0; dd < 8; ++dd) bias[dd] = bk[dkbase + dd];
    const size_t kzb = (size_t)b * 131072;
#pragma unroll
    for (int nn = 0; nn < 8; ++nn) {
      int n = n0 + nthr * 4 + (nn & 3) + (nn >> 2) * 128;
      int kk = n & 31, T = n >> 5;
      size_t base = kzb + (size_t)T * 1024 + j * 512 + khi * 256 + kk * 8;
      ushort4 a, bb;
      a.x = f2bf(acc[0][nn] + bias[0]); a.y = f2bf(acc[1][nn] + bias[1]);
      a.z = f2bf(acc[2][nn] + bias[2]); a.w = f2bf(acc[3][nn] + bias[3]);
      bb.x = f2bf(acc[4][nn] + bias[4]); bb.y = f2bf(acc[5][nn] + bias[5]);
      bb.z = f2bf(acc[6][nn] + bias[6]); bb.w = f2bf(acc[7][nn] + bias[7]);
      *(ushort4*)(ko + base) = a;
      *(ushort4*)(ko + base + 4) = bb;
    }
  } else {
    const int cbase = (dt - 1) * 64 + dthr * 8;
    const int kk4 = (nthr * 4) & 31;
    const int T0 = (n0 + nthr * 4) >> 5;
    const int vhi = (kk4 >> 3) & 1;
    const int i4 = kk4 & 7;
    const size_t vzb = (size_t)b * 1048576;
#pragma unroll
    for (int dd = 0; dd < 8; ++dd) {
      int c = cbase + dd;
      float bias = bv[c];
      int jj = (c >> 5) * 2 + (kk4 >> 4);
      int l = c & 31;
      size_t off0 = vzb + (size_t)T0 * 8192 + (size_t)jj * 512 + vhi * 256 + l * 8 + i4;
      ushort4 w0, w1;
      w0.x = f2bf(acc[dd][0] + bias); w0.y = f2bf(acc[dd][1] + bias);
      w0.z = f2bf(acc[dd][2] + bias); w0.w = f2bf(acc[dd][3] + bias);
      w1.x = f2bf(acc[dd][4] + bias); w1.y = f2bf(acc[dd][5] + bias);
      w1.z = f2bf(acc[dd][6] + bias); w1.w = f2bf(acc[dd][7] + bias);
      *(ushort4*)(vo + off0) = w0;
      *(ushort4*)(vo + off0 + 4 * 8192) = w1;
    }
  }
}

// ---------------------------------------------------------------------------
// online softmax + P pack; rescales the SELF accumulator internally, returns
// the rescale factor aa (1.0f if deferred) so the partner wave can apply it
// to its copy of this mset's accumulation. All acc indices compile-time.
// ---------------------------------------------------------------------------
static __device__ __forceinline__ float softmax_pack4(
    f32x16& s, float& mrun, float& lsum, f32x16 (&acc)[4],
    bf16x8& pb0o, bf16x8& pb1o)
{
  float pm = s[0];
#pragma unroll
  for (int r = 1; r < 16; ++r) pm = fmaxf(pm, s[r]);
  pm = fmaxf(pm, __shfl_xor(pm, 32));

  float aa = 1.0f;
  if (!__all(pm <= mrun + 8.0f)) {              // defer-max (T13), log2 domain
    float mnew = fmaxf(mrun, pm);
    aa = EXP2(mrun - mnew);
    mrun = mnew;
    lsum *= aa;
#pragma unroll
    for (int q = 0; q < 4; ++q)
#pragma unroll
      for (int r = 0; r < 16; ++r) acc[q][r] *= aa;
  }

  float p[16];
  float ps = 0.f;
#pragma unroll
  for (int r = 0; r < 16; ++r) { p[r] = EXP2(s[r] - mrun); ps += p[r]; }
  ps += __shfl_xor(ps, 32);
  lsum += ps;

  uint pw[8];
#pragma unroll
  for (int j = 0; j < 8; ++j) pw[j] = cvtpk_bf16(p[2 * j], p[2 * j + 1]);
  plswap(pw[0], pw[2]); plswap(pw[1], pw[3]);
  plswap(pw[4], pw[6]); plswap(pw[5], pw[7]);
  union { uint u[4]; bf16x8 v; } pb0u, pb1u;
  pb0u.u[0] = pw[0]; pb0u.u[1] = pw[1]; pb0u.u[2] = pw[2]; pb0u.u[3] = pw[3];
  pb1u.u[0] = pw[4]; pb1u.u[1] = pw[5]; pb1u.u[2] = pw[6]; pb1u.u[3] = pw[7];
  pb0o = pb0u.v; pb1o = pb1u.v;
  return aa;
}

// ---------------------------------------------------------------------------
// Kernel 2: fused flash attention + residual. v8: P-EXCHANGE.
// Block = 128 thr = 2 waves (ch = c-half). Group = 64 m. Wave ch softmaxes
// ONLY mset ch (32 m — no duplicated softmax) and PVs BOTH msets over its
// private c-half: accS[4] (self mset) + accP[4] (partner mset) = 128 regs.
// Packed P (8 dwords/lane) + rescale factor exchanged via LDS with a
// 2-barrier handshake (raw s_barrier: does NOT drain vmcnt). V streams stay
// per-wave private via gload_lds, counted vmcnt(10); K prefetched into regs.
// Each V byte now feeds 64 m -> L2 traffic 2.3 GB -> 1.2 GB. 512 blocks =
// 4/CU (37.5 KB LDS) = 8 waves/CU = 2/SIMD. Epilogue: lsum swap only (each
// wave holds full-key results for its c-half x both msets).
// ---------------------------------------------------------------------------
__global__ __launch_bounds__(128, 2) void attn_fused(
    const ushort* __restrict__ qs, const ushort* __restrict__ kz,
    const ushort* __restrict__ vz, const float* __restrict__ x,
    const float* __restrict__ gamma, float* __restrict__ out)
{
  __shared__ __align__(16) ushort vbuf[2][2][4096];  // [wave][parity][8KB] 32 KB
  __shared__ uint  pexch[2][8][64];                  // packed P          4 KB
  __shared__ float afac[2][64];                      // rescale factors  .5 KB
  __shared__ float sml[2][64];                       // final lsum swap  .5 KB

  const int wg = blockIdx.x;                      // 0..511
  const int swz = (wg & 7) * 64 + (wg >> 3);      // one batch per XCD
  const int b = swz >> 6, gt = swz & 63;          // 64-m group
  const int tid = threadIdx.x;
  const int ch = tid >> 6, lane = tid & 63;       // ch = wave = c-half = mset
  const int l31 = lane & 31, hi = lane >> 5;
  const int mSelf = gt * 64 + ch * 32 + l31;

  // resident Q B-frags for MY mset only
  const ushort* qcol = qs + (size_t)b * 131072 + mSelf;
  bf16x8 qf0, qf1;
  {
    union { ushort s[8]; bf16x8 v; } u0, u1;
#pragma unroll
    for (int i = 0; i < 8; ++i) {
      u0.s[i] = qcol[(size_t)(8 * hi + i) * 4096];
      u1.s[i] = qcol[(size_t)(16 + 8 * hi + i) * 4096];
    }
    qf0 = u0.v; qf1 = u1.v;
  }

  const ushort* kb = kz + (size_t)b * 131072;
  const ushort* vb = vz + (size_t)b * 1048576;

  f32x16 accS[4], accP[4];
#pragma unroll
  for (int q = 0; q < 4; ++q)
#pragma unroll
    for (int r = 0; r < 16; ++r) { accS[q][r] = 0.f; accP[q][r] = 0.f; }

  const f32x16 fzero = {};
  float mrun = -1e30f, lsum = 0.f;

  // V stream: my c-half = 8 KB per tile, linear into vbuf[ch][parity]
  auto ISSUE_V = [&](int t, int par) {
#pragma unroll
    for (int i = 0; i < 8; ++i)
      gload16(vb + (size_t)t * 8192 + (size_t)(ch * 8 + i) * 512 + lane * 8,
              &vbuf[ch][par][i * 512]);
  };
  // K prefetch into regs (2 x dwordx4 per tile)
  auto LOADK0 = [&](int t) {
    return *(const uint4*)(kb + (size_t)t * 1024 + lane * 8);
  };
  auto LOADK1 = [&](int t) {
    return *(const uint4*)(kb + (size_t)t * 1024 + 512 + lane * 8);
  };

  uint4 kA0, kA1, kB0, kB1;   // K regs, parity-named (rule #20)
  ISSUE_V(0, 0); kA0 = LOADK0(0); kA1 = LOADK1(0);
  ISSUE_V(1, 1); kB0 = LOADK0(1); kB1 = LOADK1(1);

  // one tile body; issues exactly 10 vmem ops when DO_ISSUE
#define BODY(T, PAR, K0, K1, WAITN, DO_ISSUE)                                  \
  {                                                                            \
    asm volatile("s_waitcnt vmcnt(" #WAITN ")" ::: "memory");                  \
    union { uint4 u; bf16x8 v; } kc0, kc1;                                     \
    kc0.u = K0; kc1.u = K1;                                                    \
    f32x16 s = __builtin_amdgcn_mfma_f32_32x32x16_bf16(kc0.v, qf0, fzero, 0, 0, 0); \
    s = __builtin_amdgcn_mfma_f32_32x32x16_bf16(kc1.v, qf1, s, 0, 0, 0);       \
    bf16x8 pbS0, pbS1;                                                         \
    float aa = softmax_pack4(s, mrun, lsum, accS, pbS0, pbS1);                 \
    union { uint u[4]; bf16x8 v; } w0, w1;                                     \
    w0.v = pbS0; w1.v = pbS1;                                                  \
    pexch[ch][0][lane] = w0.u[0]; pexch[ch][1][lane] = w0.u[1];                \
    pexch[ch][2][lane] = w0.u[2]; pexch[ch][3][lane] = w0.u[3];                \
    pexch[ch][4][lane] = w1.u[0]; pexch[ch][5][lane] = w1.u[1];                \
    pexch[ch][6][lane] = w1.u[2]; pexch[ch][7][lane] = w1.u[3];                \
    afac[ch][lane] = aa;                                                       \
    asm volatile("s_waitcnt lgkmcnt(0)" ::: "memory");                         \
    __builtin_amdgcn_s_barrier();                                              \
    union { uint u[4]; bf16x8 v; } r0, r1;                                     \
    r0.u[0] = pexch[ch ^ 1][0][lane]; r0.u[1] = pexch[ch ^ 1][1][lane];        \
    r0.u[2] = pexch[ch ^ 1][2][lane]; r0.u[3] = pexch[ch ^ 1][3][lane];        \
    r1.u[0] = pexch[ch ^ 1][4][lane]; r1.u[1] = pexch[ch ^ 1][5][lane];        \
    r1.u[2] = pexch[ch ^ 1][6][lane]; r1.u[3] = pexch[ch ^ 1][7][lane];        \
    float aaP = afac[ch ^ 1][lane];                                            \
    asm volatile("s_waitcnt lgkmcnt(0)" ::: "memory");                         \
    __builtin_amdgcn_s_barrier();                                              \
    bf16x8 pbP0 = r0.v, pbP1 = r1.v;                                           \
    if (!__all(aaP == 1.0f)) {                                                 \
      _Pragma("unroll")                                                        \
      for (int q = 0; q < 4; ++q)                                              \
        _Pragma("unroll")                                                      \
        for (int r = 0; r < 16; ++r) accP[q][r] *= aaP;                        \
    }                                                                          \
    __builtin_amdgcn_s_setprio(1);                                             \
    _Pragma("unroll")                                                          \
    for (int q = 0; q < 4; ++q) {                                              \
      bf16x8 va0 = *(const bf16x8*)&vbuf[ch][PAR][(q * 2 + 0) * 512 + lane * 8]; \
      bf16x8 va1 = *(const bf16x8*)&vbuf[ch][PAR][(q * 2 + 1) * 512 + lane * 8]; \
      accS[q] = __builtin_amdgcn_mfma_f32_32x32x16_bf16(va0, pbS0, accS[q], 0, 0, 0); \
      accP[q] = __builtin_amdgcn_mfma_f32_32x32x16_bf16(va0, pbP0, accP[q], 0, 0, 0); \
      accS[q] = __builtin_amdgcn_mfma_f32_32x32x16_bf16(va1, pbS1, accS[q], 0, 0, 0); \
      accP[q] = __builtin_amdgcn_mfma_f32_32x32x16_bf16(va1, pbP1, accP[q], 0, 0, 0); \
    }                                                                          \
    __builtin_amdgcn_s_setprio(0);                                             \
    if (DO_ISSUE) {                                                            \
      ISSUE_V((T) + 2, PAR);                                                   \
      if ((PAR) == 0) { kA0 = LOADK0((T) + 2); kA1 = LOADK1((T) + 2); }        \
      else            { kB0 = LOADK0((T) + 2); kB1 = LOADK1((T) + 2); }        \
    }                                                                          \
  }

  for (int tt = 0; tt < 63; ++tt) {
    const int t = tt * 2;
    BODY(t, 0, kA0, kA1, 10, true);
    BODY(t + 1, 1, kB0, kB1, 10, true);
  }
  BODY(126, 0, kA0, kA1, 10, false);
  BODY(127, 1, kB0, kB1, 0, false);
#undef BODY

  // ---- epilogue: swap final lsum, normalize, gamma*out + x ----
  sml[ch][lane] = lsum;
  asm volatile("s_waitcnt lgkmcnt(0)" ::: "memory");
  __builtin_amdgcn_s_barrier();
  const float lsumP = sml[ch ^ 1][lane];
  const float invS = 1.0f / lsum, invP = 1.0f / lsumP;
  const float g = gamma[0];
  const int mP = gt * 64 + (ch ^ 1) * 32 + l31;
  const float* xcS = x + (size_t)b * 256 * 4096 + mSelf;
  float* ocS = out + (size_t)b * 256 * 4096 + mSelf;
  const float* xcP = x + (size_t)b * 256 * 4096 + mP;
  float* ocP = out + (size_t)b * 256 * 4096 + mP;
#pragma unroll
  for (int q = 0; q < 4; ++q) {
#pragma unroll
    for (int r = 0; r < 16; ++r) {
      int c = ch * 128 + q * 32 + (r & 3) + 8 * (r >> 2) + 4 * hi;
      ocS[(size_t)c * 4096] = g * (accS[q][r] * invS) + xcS[(size_t)c * 4096];
      ocP[(size_t)c * 4096] = g * (accP[q][r] * invP) + xcP[(size_t)c * 4096];
    }
  }
}

extern "C" void kernel_launch(void* const* d_in, const int* in_sizes, int n_in,
                              void* d_out, int out_size, void* d_ws, size_t ws_size,
                              hipStream_t stream) {
  const float* x  = (const float*)d_in[0];
  const float* Wq = (const float*)d_in[1];
  const float* bq = (const float*)d_in[2];
  const float* Wk = (const float*)d_in[3];
  const float* bk = (const float*)d_in[4];
  const float* Wv = (const float*)d_in[5];
  const float* bv = (const float*)d_in[6];
  const float* gm = (const float*)d_in[7];
  float* out = (float*)d_out;

  ushort* qs = (ushort*)d_ws;
  ushort* kzp = qs + (size_t)8 * 131072;
  ushort* vzp = kzp + (size_t)8 * 131072;

  proj_qkv<<<dim3(16, 8, 5), 256, 0, stream>>>(x, Wq, bq, Wk, bk, Wv, bv, qs, kzp, vzp);
  attn_fused<<<dim3(512), 128, 0, stream>>>(qs, kzp, vzp, x, gm, out);
}

// Round 9
// 186.392 us; speedup vs baseline: 2.2102x; 1.2273x over previous
//
#include <hip/hip_runtime.h>
#include <cstdint>

typedef __bf16 bf16x8 __attribute__((ext_vector_type(8)));
typedef float f32x16 __attribute__((ext_vector_type(16)));

#define LOG2E 1.44269504088896340736f

static __device__ __forceinline__ ushort f2bf(float f) {
  uint u = __builtin_bit_cast(uint, f);
  u = u + 0x7FFFu + ((u >> 16) & 1u);   // RNE
  return (ushort)(u >> 16);
}

static __device__ __forceinline__ uint cvtpk_bf16(float lo, float hi) {
  uint r;
  asm("v_cvt_pk_bf16_f32 %0, %1, %2" : "=v"(r) : "v"(lo), "v"(hi));
  return r;
}

static __device__ __forceinline__ void plswap(uint& a, uint& b) {
  asm("v_permlane32_swap_b32 %0, %1" : "+v"(a), "+v"(b));
}

// async global->LDS, 16B per lane; LDS dest wave-uniform base + lane*16.
static __device__ __forceinline__ void gload16(const ushort* g, ushort* l) {
  __builtin_amdgcn_global_load_lds(
      (const __attribute__((address_space(1))) void*)g,
      (__attribute__((address_space(3))) void*)l, 16, 0, 0);
}

#if __has_builtin(__builtin_amdgcn_exp2f)
#define EXP2(x) __builtin_amdgcn_exp2f(x)
#else
#define EXP2(x) exp2f(x)
#endif

// ---------------------------------------------------------------------------
// Workspace layouts (all bf16 as ushort):
//   qs : [b][32 d][4096 m]                      (2 MB)
//   kz : [b][128 T][frag j(2)][lane(64)][i(8)]  (2 MB)  K-tile fragment-major
//   vz : [b][128 T][frag j(16)][lane(64)][i(8)] (16 MB) V-tile fragment-major
// A-frag convention (verified R1): lane holds A[row=l31][k=8*hi+i].
// ---------------------------------------------------------------------------

__global__ __launch_bounds__(256, 2) void proj_qkv(
    const float* __restrict__ x,
    const float* __restrict__ Wq, const float* __restrict__ bq,
    const float* __restrict__ Wk, const float* __restrict__ bk,
    const float* __restrict__ Wv, const float* __restrict__ bv,
    ushort* __restrict__ qo, ushort* __restrict__ ko, ushort* __restrict__ vo)
{
  __shared__ float xs[32][256];   // [c][n]
  __shared__ float wt[32][64];    // [c][d] (transposed W chunk)

  const int tid = threadIdx.x;
  const int nt = blockIdx.x, b = blockIdx.y, dt = blockIdx.z;
  const int n0 = nt * 256;
  const int nthr = tid & 31;
  const int dthr = tid >> 5;

  float acc[8][8];
#pragma unroll
  for (int i = 0; i < 8; ++i)
#pragma unroll
    for (int j = 0; j < 8; ++j) acc[i][j] = 0.f;

  const float* xb = x + (size_t)b * 256 * 4096;

  for (int kc = 0; kc < 8; ++kc) {
    const int c0 = kc * 32;
    __syncthreads();
#pragma unroll
    for (int r = 0; r < 8; ++r) {
      int id = r * 256 + tid;
      int c = id >> 6, pos = (id & 63) * 4;
      float4 v = *(const float4*)(xb + (size_t)(c0 + c) * 4096 + n0 + pos);
      *(float4*)&xs[c][pos] = v;
    }
#pragma unroll
    for (int r = 0; r < 2; ++r) {
      int id = r * 256 + tid;
      int d = id >> 3, c4 = (id & 7) * 4;
      int grow = dt * 64 + d;
      const float* wrow;
      float scale = 1.f;
      if (dt == 0) {
        if (grow < 32) { wrow = Wq + (size_t)grow * 256; scale = LOG2E; }
        else           { wrow = Wk + (size_t)(grow - 32) * 256; }
      } else {
        wrow = Wv + (size_t)(grow - 64) * 256;
      }
      float4 v = *(const float4*)(wrow + c0 + c4);
      wt[c4 + 0][d] = v.x * scale;
      wt[c4 + 1][d] = v.y * scale;
      wt[c4 + 2][d] = v.z * scale;
      wt[c4 + 3][d] = v.w * scale;
    }
    __syncthreads();

#pragma unroll
    for (int cc = 0; cc < 32; ++cc) {
      float4 xv0 = *(const float4*)&xs[cc][nthr * 4];
      float4 xv1 = *(const float4*)&xs[cc][nthr * 4 + 128];
      float4 wv0 = *(const float4*)&wt[cc][dthr * 8];
      float4 wv1 = *(const float4*)&wt[cc][dthr * 8 + 4];
      float wr[8] = {wv0.x, wv0.y, wv0.z, wv0.w, wv1.x, wv1.y, wv1.z, wv1.w};
      float xr[8] = {xv0.x, xv0.y, xv0.z, xv0.w, xv1.x, xv1.y, xv1.z, xv1.w};
#pragma unroll
      for (int dd = 0; dd < 8; ++dd)
#pragma unroll
        for (int nn = 0; nn < 8; ++nn)
          acc[dd][nn] = fmaf(wr[dd], xr[nn], acc[dd][nn]);
    }
  }

  // ---- epilogue ----
  if (dt == 0 && dthr < 4) {
#pragma unroll
    for (int dd = 0; dd < 8; ++dd) {
      int grow = dthr * 8 + dd;
      ushort* dst = qo + ((size_t)b * 32 + grow) * 4096;
      float bias = bq[grow] * LOG2E;
      ushort4 w0, w1;
      w0.x = f2bf(acc[dd][0] + bias); w0.y = f2bf(acc[dd][1] + bias);
      w0.z = f2bf(acc[dd][2] + bias); w0.w = f2bf(acc[dd][3] + bias);
      w1.x = f2bf(acc[dd][4] + bias); w1.y = f2bf(acc[dd][5] + bias);
      w1.z = f2bf(acc[dd][6] + bias); w1.w = f2bf(acc[dd][7] + bias);
      *(ushort4*)(dst + n0 + nthr * 4) = w0;
      *(ushort4*)(dst + n0 + nthr * 4 + 128) = w1;
    }
  } else if (dt == 0) {
    const int dkbase = (dthr - 4) * 8;
    const int j = dkbase >> 4;
    const int khi = (dkbase >> 3) & 1;
    float bias[8];
#pragma unroll
    for (int dd = 0; dd < 8; ++dd) bias[dd] = bk[dkbase + dd];
    const size_t kzb = (size_t)b * 131072;
#pragma unroll
    for (int nn = 0; nn < 8; ++nn) {
      int n = n0 + nthr * 4 + (nn & 3) + (nn >> 2) * 128;
      int kk = n & 31, T = n >> 5;
      size_t base = kzb + (size_t)T * 1024 + j * 512 + khi * 256 + kk * 8;
      ushort4 a, bb;
      a.x = f2bf(acc[0][nn] + bias[0]); a.y = f2bf(acc[1][nn] + bias[1]);
      a.z = f2bf(acc[2][nn] + bias[2]); a.w = f2bf(acc[3][nn] + bias[3]);
      bb.x = f2bf(acc[4][nn] + bias[4]); bb.y = f2bf(acc[5][nn] + bias[5]);
      bb.z = f2bf(acc[6][nn] + bias[6]); bb.w = f2bf(acc[7][nn] + bias[7]);
      *(ushort4*)(ko + base) = a;
      *(ushort4*)(ko + base + 4) = bb;
    }
  } else {
    const int cbase = (dt - 1) * 64 + dthr * 8;
    const int kk4 = (nthr * 4) & 31;
    const int T0 = (n0 + nthr * 4) >> 5;
    const int vhi = (kk4 >> 3) & 1;
    const int i4 = kk4 & 7;
    const size_t vzb = (size_t)b * 1048576;
#pragma unroll
    for (int dd = 0; dd < 8; ++dd) {
      int c = cbase + dd;
      float bias = bv[c];
      int jj = (c >> 5) * 2 + (kk4 >> 4);
      int l = c & 31;
      size_t off0 = vzb + (size_t)T0 * 8192 + (size_t)jj * 512 + vhi * 256 + l * 8 + i4;
      ushort4 w0, w1;
      w0.x = f2bf(acc[dd][0] + bias); w0.y = f2bf(acc[dd][1] + bias);
      w0.z = f2bf(acc[dd][2] + bias); w0.w = f2bf(acc[dd][3] + bias);
      w1.x = f2bf(acc[dd][4] + bias); w1.y = f2bf(acc[dd][5] + bias);
      w1.z = f2bf(acc[dd][6] + bias); w1.w = f2bf(acc[dd][7] + bias);
      *(ushort4*)(vo + off0) = w0;
      *(ushort4*)(vo + off0 + 4 * 8192) = w1;
    }
  }
}

// ---------------------------------------------------------------------------
// online softmax + P pack only (no acc rescale — that goes through the afac
// all-to-all path). Returns rescale factor aa (1.0f if deferred).
// ---------------------------------------------------------------------------
static __device__ __forceinline__ float softmax_pack_only(
    f32x16& s, float& mrun, float& lsum, bf16x8& pb0o, bf16x8& pb1o)
{
  float pm = s[0];
#pragma unroll
  for (int r = 1; r < 16; ++r) pm = fmaxf(pm, s[r]);
  pm = fmaxf(pm, __shfl_xor(pm, 32));

  float aa = 1.0f;
  if (!__all(pm <= mrun + 8.0f)) {              // defer-max (T13), log2 domain
    float mnew = fmaxf(mrun, pm);
    aa = EXP2(mrun - mnew);
    mrun = mnew;
    lsum *= aa;
  }

  float p[16];
  float ps = 0.f;
#pragma unroll
  for (int r = 0; r < 16; ++r) { p[r] = EXP2(s[r] - mrun); ps += p[r]; }
  ps += __shfl_xor(ps, 32);
  lsum += ps;

  uint pw[8];
#pragma unroll
  for (int j = 0; j < 8; ++j) pw[j] = cvtpk_bf16(p[2 * j], p[2 * j + 1]);
  plswap(pw[0], pw[2]); plswap(pw[1], pw[3]);
  plswap(pw[4], pw[6]); plswap(pw[5], pw[7]);
  union { uint u[4]; bf16x8 v; } pb0u, pb1u;
  pb0u.u[0] = pw[0]; pb0u.u[1] = pw[1]; pb0u.u[2] = pw[2]; pb0u.u[3] = pw[3];
  pb1u.u[0] = pw[4]; pb1u.u[1] = pw[5]; pb1u.u[2] = pw[6]; pb1u.u[3] = pw[7];
  pb0o = pb0u.v; pb1o = pb1u.v;
  return aa;
}

// ---------------------------------------------------------------------------
// Kernel 2 v9: 8-wave all-to-all P-exchange flash attention + residual.
// Block = 512 thr = 8 waves (kh key-half, q = mset & c-quarter). 128 m/block.
// Wave (kh,q): softmax mset q over key-half kh; PV ALL 4 msets over
// c-quarter q (acc[4][2] = 128 regs). Packed P + rescale factors exchanged
// all-to-all via double-buffered LDS, ONE raw s_barrier per iter (no vmcnt
// drain). V private gload_lds 2-deep; K shared per kh, staged by waves q=0,1,
// 3-deep/4-slot ring (reader certification: B(t-1) >= stager's vmcnt(5)
// which leaves only {V(t),K(t+1)} outstanding). 256 blocks = 1/CU = 2
// waves/SIMD. Cross-kh merge at end via 64KB LDS overlay, two passes.
// ---------------------------------------------------------------------------
__global__ __launch_bounds__(512, 2) void attn_fused(
    const ushort* __restrict__ qs, const ushort* __restrict__ kz,
    const ushort* __restrict__ vz, const float* __restrict__ x,
    const float* __restrict__ gamma, float* __restrict__ out)
{
  __shared__ __align__(16) union SMem {
    ushort vbuf[8][2][2048];        // per-wave V c-quarter, dbuf   64 KB
    float  xch[4][2][2][16][64];    // epilogue acc exchange        64 KB
  } sm;
  __shared__ __align__(16) ushort kbuf[2][4][1024];  // K 4-slot ring  16 KB
  __shared__ uint  pexch[2][2][4][64][8];            // packed P       32 KB
  __shared__ float afac[2][2][4][64];                // rescale         4 KB
  __shared__ float mlbuf[2][4][2][64];               // (m,l) final     4 KB

  const int wg = blockIdx.x;                      // 0..255
  const int swz = (wg & 7) * 32 + (wg >> 3);      // one batch per XCD
  const int b = swz >> 5, mt = swz & 31;
  const int tid = threadIdx.x;
  const int wv = tid >> 6, lane = tid & 63;
  const int kh = wv >> 2, q = wv & 3;
  const int l31 = lane & 31, hi = lane >> 5;
  const int mbase = mt * 128;
  const int mSelf = mbase + q * 32 + l31;

  // resident Q B-frags for mset q
  const ushort* qcol = qs + (size_t)b * 131072 + mSelf;
  bf16x8 qf0, qf1;
  {
    union { ushort s[8]; bf16x8 v; } u0, u1;
#pragma unroll
    for (int i = 0; i < 8; ++i) {
      u0.s[i] = qcol[(size_t)(8 * hi + i) * 4096];
      u1.s[i] = qcol[(size_t)(16 + 8 * hi + i) * 4096];
    }
    qf0 = u0.v; qf1 = u1.v;
  }

  const ushort* kb = kz + (size_t)b * 131072 + (size_t)kh * 64 * 1024;
  const ushort* vb = vz + (size_t)b * 1048576 + (size_t)kh * 64 * 8192;

  f32x16 acc[4][2];
#pragma unroll
  for (int mu = 0; mu < 4; ++mu)
#pragma unroll
    for (int cf = 0; cf < 2; ++cf)
#pragma unroll
      for (int r = 0; r < 16; ++r) acc[mu][cf][r] = 0.f;

  const f32x16 fzero = {};
  float mrun = -1e30f, lsum = 0.f;

  // V: 4 gloads (c-quarter, 4KB) into private vbuf[wv][par]
  auto ISSUE_V = [&](int t, int par) {
#pragma unroll
    for (int i = 0; i < 4; ++i)
      gload16(vb + (size_t)t * 8192 + (size_t)(q * 4 + i) * 512 + lane * 8,
              &sm.vbuf[wv][par][i * 512]);
  };
  // K: waves q=0,1 each stage one 512-ushort frag into the 4-slot ring
  auto ISSUE_K = [&](int t) {
    if (q < 2)
      gload16(kb + (size_t)t * 1024 + (size_t)q * 512 + lane * 8,
              &kbuf[kh][t & 3][q * 512]);
  };

  // prologue: V(0) K(0) K(1) V(1) K(2)  [q<2: 11 ops, q>=2: 8 ops]
  ISSUE_V(0, 0);
  ISSUE_K(0);
  ISSUE_K(1);
  ISSUE_V(1, 1);
  ISSUE_K(2);
  if (q < 2) { asm volatile("s_waitcnt vmcnt(5)" ::: "memory"); }
  else       { asm volatile("s_waitcnt vmcnt(4)" ::: "memory"); }
  __builtin_amdgcn_s_barrier();   // certifies K(0) for all waves

#define BODY(T, W01, W23)                                                      \
  {                                                                            \
    const int t_ = (T);                                                        \
    const int vpar = t_ & 1, kslot = t_ & 3, xpar = t_ & 1;                    \
    if (q < 2) { asm volatile("s_waitcnt vmcnt(" #W01 ")" ::: "memory"); }     \
    else       { asm volatile("s_waitcnt vmcnt(" #W23 ")" ::: "memory"); }     \
    /* QK^T for mset q */                                                      \
    bf16x8 ka0 = *(const bf16x8*)&kbuf[kh][kslot][lane * 8];                   \
    bf16x8 ka1 = *(const bf16x8*)&kbuf[kh][kslot][512 + lane * 8];             \
    f32x16 s = __builtin_amdgcn_mfma_f32_32x32x16_bf16(ka0, qf0, fzero, 0, 0, 0); \
    s = __builtin_amdgcn_mfma_f32_32x32x16_bf16(ka1, qf1, s, 0, 0, 0);         \
    bf16x8 pbS0, pbS1;                                                         \
    float aa = softmax_pack_only(s, mrun, lsum, pbS0, pbS1);                   \
    { union { bf16x8 v; uint4 u; } c0, c1; c0.v = pbS0; c1.v = pbS1;           \
      *(uint4*)&pexch[kh][xpar][q][lane][0] = c0.u;                            \
      *(uint4*)&pexch[kh][xpar][q][lane][4] = c1.u; }                          \
    afac[kh][xpar][q][lane] = aa;                                              \
    asm volatile("s_waitcnt lgkmcnt(0)" ::: "memory");                         \
    __builtin_amdgcn_s_barrier();                                              \
    /* V frags once, reused by all 4 msets */                                  \
    bf16x8 va0 = *(const bf16x8*)&sm.vbuf[wv][vpar][0 * 512 + lane * 8];       \
    bf16x8 va1 = *(const bf16x8*)&sm.vbuf[wv][vpar][1 * 512 + lane * 8];       \
    bf16x8 va2 = *(const bf16x8*)&sm.vbuf[wv][vpar][2 * 512 + lane * 8];       \
    bf16x8 va3 = *(const bf16x8*)&sm.vbuf[wv][vpar][3 * 512 + lane * 8];       \
    _Pragma("unroll")                                                          \
    for (int mu = 0; mu < 4; ++mu) {                                           \
      float aaU = afac[kh][xpar][mu][lane];                                    \
      union { uint4 u; bf16x8 v; } r0, r1;                                     \
      r0.u = *(const uint4*)&pexch[kh][xpar][mu][lane][0];                     \
      r1.u = *(const uint4*)&pexch[kh][xpar][mu][lane][4];                     \
      if (!__all(aaU == 1.0f)) {                                               \
        _Pragma("unroll")                                                      \
        for (int cf = 0; cf < 2; ++cf)                                         \
          _Pragma("unroll")                                                    \
          for (int r = 0; r < 16; ++r) acc[mu][cf][r] *= aaU;                  \
      }                                                                        \
      __builtin_amdgcn_s_setprio(1);                                           \
      acc[mu][0] = __builtin_amdgcn_mfma_f32_32x32x16_bf16(va0, r0.v, acc[mu][0], 0, 0, 0); \
      acc[mu][0] = __builtin_amdgcn_mfma_f32_32x32x16_bf16(va1, r1.v, acc[mu][0], 0, 0, 0); \
      acc[mu][1] = __builtin_amdgcn_mfma_f32_32x32x16_bf16(va2, r0.v, acc[mu][1], 0, 0, 0); \
      acc[mu][1] = __builtin_amdgcn_mfma_f32_32x32x16_bf16(va3, r1.v, acc[mu][1], 0, 0, 0); \
      __builtin_amdgcn_s_setprio(0);                                           \
    }                                                                          \
    if (t_ < 62) ISSUE_V(t_ + 2, vpar);                                        \
    if (t_ < 61) ISSUE_K(t_ + 3);                                              \
  }

  for (int t = 0; t < 62; ++t) BODY(t, 5, 4);
  BODY(62, 4, 4);
  BODY(63, 0, 0);
#undef BODY

  // ---- epilogue: cross-kh merge ----
  mlbuf[kh][q][0][lane] = mrun;
  mlbuf[kh][q][1][lane] = lsum;
  asm volatile("s_waitcnt lgkmcnt(0)" ::: "memory");
  __builtin_amdgcn_s_barrier();

  const float g = gamma[0];
  const float* xc = x + (size_t)b * 256 * 4096;
  float* oc = out + (size_t)b * 256 * 4096;

  // pass A: msets 0,1 — kh1 ships, kh0 merges + stores
  if (kh == 1) {
#pragma unroll
    for (int mu = 0; mu < 2; ++mu)
#pragma unroll
      for (int cf = 0; cf < 2; ++cf)
#pragma unroll
        for (int r = 0; r < 16; ++r)
          sm.xch[q][mu][cf][r][lane] = acc[mu][cf][r];
  }
  asm volatile("s_waitcnt lgkmcnt(0)" ::: "memory");
  __builtin_amdgcn_s_barrier();
  if (kh == 0) {
#pragma unroll
    for (int mu = 0; mu < 2; ++mu) {
      float m0 = mlbuf[0][mu][0][lane], l0 = mlbuf[0][mu][1][lane];
      float m1 = mlbuf[1][mu][0][lane], l1 = mlbuf[1][mu][1][lane];
      float ms = fmaxf(m0, m1);
      float w0 = EXP2(m0 - ms), w1 = EXP2(m1 - ms);
      float inv = 1.0f / (l0 * w0 + l1 * w1);
      int m = mbase + mu * 32 + l31;
#pragma unroll
      for (int cf = 0; cf < 2; ++cf)
#pragma unroll
        for (int r = 0; r < 16; ++r) {
          float val = acc[mu][cf][r] * w0 + sm.xch[q][mu][cf][r][lane] * w1;
          int c = q * 64 + cf * 32 + (r & 3) + 8 * (r >> 2) + 4 * hi;
          oc[(size_t)c * 4096 + m] = g * (val * inv) + xc[(size_t)c * 4096 + m];
        }
    }
  }
  __builtin_amdgcn_s_barrier();
  // pass B: msets 2,3
  if (kh == 1) {
#pragma unroll
    for (int mu = 0; mu < 2; ++mu)
#pragma unroll
      for (int cf = 0; cf < 2; ++cf)
#pragma unroll
        for (int r = 0; r < 16; ++r)
          sm.xch[q][mu][cf][r][lane] = acc[2 + mu][cf][r];
  }
  asm volatile("s_waitcnt lgkmcnt(0)" ::: "memory");
  __builtin_amdgcn_s_barrier();
  if (kh == 0) {
#pragma unroll
    for (int mu = 0; mu < 2; ++mu) {
      float m0 = mlbuf[0][2 + mu][0][lane], l0 = mlbuf[0][2 + mu][1][lane];
      float m1 = mlbuf[1][2 + mu][0][lane], l1 = mlbuf[1][2 + mu][1][lane];
      float ms = fmaxf(m0, m1);
      float w0 = EXP2(m0 - ms), w1 = EXP2(m1 - ms);
      float inv = 1.0f / (l0 * w0 + l1 * w1);
      int m = mbase + (2 + mu) * 32 + l31;
#pragma unroll
      for (int cf = 0; cf < 2; ++cf)
#pragma unroll
        for (int r = 0; r < 16; ++r) {
          float val = acc[2 + mu][cf][r] * w0 + sm.xch[q][mu][cf][r][lane] * w1;
          int c = q * 64 + cf * 32 + (r & 3) + 8 * (r >> 2) + 4 * hi;
          oc[(size_t)c * 4096 + m] = g * (val * inv) + xc[(size_t)c * 4096 + m];
        }
    }
  }
}

extern "C" void kernel_launch(void* const* d_in, const int* in_sizes, int n_in,
                              void* d_out, int out_size, void* d_ws, size_t ws_size,
                              hipStream_t stream) {
  const float* x  = (const float*)d_in[0];
  const float* Wq = (const float*)d_in[1];
  const float* bq = (const float*)d_in[2];
  const float* Wk = (const float*)d_in[3];
  const float* bk = (const float*)d_in[4];
  const float* Wv = (const float*)d_in[5];
  const float* bv = (const float*)d_in[6];
  const float* gm = (const float*)d_in[7];
  float* out = (float*)d_out;

  ushort* qs = (ushort*)d_ws;
  ushort* kzp = qs + (size_t)8 * 131072;
  ushort* vzp = kzp + (size_t)8 * 131072;

  proj_qkv<<<dim3(16, 8, 5), 256, 0, stream>>>(x, Wq, bq, Wk, bk, Wv, bv, qs, kzp, vzp);
  attn_fused<<<dim3(256), 512, 0, stream>>>(qs, kzp, vzp, x, gm, out);
}

// Round 10
// 138.695 us; speedup vs baseline: 2.9703x; 1.3439x over previous
//
#include <hip/hip_runtime.h>
#include <cstdint>

typedef __bf16 bf16x8 __attribute__((ext_vector_type(8)));
typedef float f32x16 __attribute__((ext_vector_type(16)));

#define LOG2E 1.44269504088896340736f

static __device__ __forceinline__ ushort f2bf(float f) {
  uint u = __builtin_bit_cast(uint, f);
  u = u + 0x7FFFu + ((u >> 16) & 1u);   // RNE
  return (ushort)(u >> 16);
}

static __device__ __forceinline__ uint cvtpk_bf16(float lo, float hi) {
  uint r;
  asm("v_cvt_pk_bf16_f32 %0, %1, %2" : "=v"(r) : "v"(lo), "v"(hi));
  return r;
}

static __device__ __forceinline__ void plswap(uint& a, uint& b) {
  asm("v_permlane32_swap_b32 %0, %1" : "+v"(a), "+v"(b));
}

// async global->LDS, 16B per lane; LDS dest wave-uniform base + lane*16.
static __device__ __forceinline__ void gload16(const ushort* g, ushort* l) {
  __builtin_amdgcn_global_load_lds(
      (const __attribute__((address_space(1))) void*)g,
      (__attribute__((address_space(3))) void*)l, 16, 0, 0);
}

#if __has_builtin(__builtin_amdgcn_exp2f)
#define EXP2(x) __builtin_amdgcn_exp2f(x)
#else
#define EXP2(x) exp2f(x)
#endif

// ---------------------------------------------------------------------------
// Workspace layouts (all bf16 as ushort):
//   qs2: [b][4096 m][32 d]                      (2 MB)  row-per-pixel
//   kz : [b][128 T][frag j(2)][lane(64)][i(8)]  (2 MB)  K-tile fragment-major
//   vz : [b][128 T][frag j(16)][lane(64)][i(8)] (16 MB) V-tile fragment-major
// A-frag convention (verified R1): lane holds A[row=l31][k=8*hi+i].
// C-layout (m74/m101): col=lane&31, row=(r&3)+8*(r>>2)+4*(lane>>5).
// ---------------------------------------------------------------------------

// ---------------------------------------------------------------------------
// Kernel 1 v2: MFMA projections. C[n][d] = mfma(A = x^T frag, B = W frag).
// Block 256 thr / 4 waves: wave w -> d-half (w&1), n-half (w>>1) of a
// 64d x 256n tile. W resident as 16 B-frags (fp32->bf16 cvt_pk, 64 VGPR).
// x staged per 32-ci chunk into LDS in A-frag layout, XOR-swizzled
// (addr ^= (qd&6)<<2) so staging b128 writes AND frag b128 reads are
// beat-conflict-free; double-buffered, reg-staged (T14).
// Epilogues: V -> vz direct (512B-contiguous stores); K -> kz scalar;
// Q -> LDS transpose (pad-40) -> qs2 coalesced 16B stores.
// ---------------------------------------------------------------------------
__global__ __launch_bounds__(256, 2) void proj_qkv(
    const float* __restrict__ x,
    const float* __restrict__ Wq, const float* __restrict__ bq,
    const float* __restrict__ Wk, const float* __restrict__ bk,
    const float* __restrict__ Wv, const float* __restrict__ bv,
    ushort* __restrict__ qo, ushort* __restrict__ ko, ushort* __restrict__ vo)
{
  __shared__ __align__(16) union SM {
    ushort xc[2][8192];        // 32 KB chunk dbuf (A-frag layout, swizzled)
    ushort qT[256 * 40];       // 20 KB q transpose overlay (post-loop)
  } sm;

  const int tid = threadIdx.x;
  const int nt = blockIdx.x, b = blockIdx.y, dt = blockIdx.z;
  const int n0 = nt * 256;
  const int wv = tid >> 6, lane = tid & 63;
  const int l31 = lane & 31, hi = lane >> 5;
  const int dh = wv & 1, nh = wv >> 1;

  // ---- W resident B-frags: lane col = d = l31, k = ci ----
  const float* wrow;
  float wsc = 1.0f;
  if (dt == 0) {
    if (dh == 0) { wrow = Wq + (size_t)l31 * 256; wsc = LOG2E; }
    else         { wrow = Wk + (size_t)l31 * 256; }
  } else {
    wrow = Wv + (size_t)((dt - 1) * 64 + dh * 32 + l31) * 256;
  }
  bf16x8 wf[16];
#pragma unroll
  for (int s = 0; s < 16; ++s) {
    float4 a = *(const float4*)(wrow + s * 16 + 8 * hi);
    float4 c = *(const float4*)(wrow + s * 16 + 8 * hi + 4);
    union { uint u[4]; bf16x8 v; } t;
    t.u[0] = cvtpk_bf16(a.x * wsc, a.y * wsc);
    t.u[1] = cvtpk_bf16(a.z * wsc, a.w * wsc);
    t.u[2] = cvtpk_bf16(c.x * wsc, c.y * wsc);
    t.u[3] = cvtpk_bf16(c.z * wsc, c.w * wsc);
    wf[s] = t.v;
  }

  f32x16 acc[4];
#pragma unroll
  for (int Tl = 0; Tl < 4; ++Tl)
#pragma unroll
    for (int r = 0; r < 16; ++r) acc[Tl][r] = 0.f;

  const float* xb = x + (size_t)b * 256 * 4096;

  // staging role: wave = ci-octet o, lane = n-quad qd
  const int o = wv, qd = lane;
  float4 xr[8];

  auto XLOAD = [&](int kc) {
    const float* src = xb + (size_t)(kc * 32 + 8 * o) * 4096 + n0 + 4 * qd;
#pragma unroll
    for (int j = 0; j < 8; ++j) xr[j] = *(const float4*)(src + (size_t)j * 4096);
  };
  auto XWRITE = [&](int buf) {
    const int base = (qd >> 3) * 1024 + (o >> 1) * 512 + (o & 1) * 256 + (qd & 7) * 32;
    const int xsw = (qd & 6) << 2;
#pragma unroll
    for (int e = 0; e < 4; ++e) {
      uint4 w;
      w.x = cvtpk_bf16(xr[0][e], xr[1][e]);
      w.y = cvtpk_bf16(xr[2][e], xr[3][e]);
      w.z = cvtpk_bf16(xr[4][e], xr[5][e]);
      w.w = cvtpk_bf16(xr[6][e], xr[7][e]);
      *(uint4*)&sm.xc[buf][(base + e * 8) ^ xsw] = w;
    }
  };

  // per-lane A-frag read offset (XOR matches staging swizzle)
  const int rdoff = (lane * 8) ^ (((l31 >> 2) & 6) << 2);

  XLOAD(0);
  asm volatile("s_waitcnt vmcnt(0)" ::: "memory");
  XWRITE(0);
  __syncthreads();

  for (int kc = 0; kc < 8; ++kc) {
    if (kc < 7) XLOAD(kc + 1);
    const ushort* buf = sm.xc[kc & 1];
#pragma unroll
    for (int s2 = 0; s2 < 2; ++s2) {
#pragma unroll
      for (int Tl = 0; Tl < 4; ++Tl) {
        const int T = nh * 4 + Tl;
        bf16x8 a = *(const bf16x8*)&buf[T * 1024 + s2 * 512 + rdoff];
        if (s2 == 0)
          acc[Tl] = __builtin_amdgcn_mfma_f32_32x32x16_bf16(a, wf[kc * 2 + 0], acc[Tl], 0, 0, 0);
        else
          acc[Tl] = __builtin_amdgcn_mfma_f32_32x32x16_bf16(a, wf[kc * 2 + 1], acc[Tl], 0, 0, 0);
      }
    }
    if (kc < 7) {
      asm volatile("s_waitcnt vmcnt(0)" ::: "memory");
      XWRITE((kc + 1) & 1);
    }
    __syncthreads();
  }

  // ---- epilogues ----
  if (dt == 0) {
    if (dh == 0) {
      // q: acc -> LDS transpose (rows padded to 40 ushorts)
      const float bq_ = bq[l31] * LOG2E;
#pragma unroll
      for (int Tl = 0; Tl < 4; ++Tl)
#pragma unroll
        for (int r = 0; r < 16; ++r) {
          int nl = (nh * 4 + Tl) * 32 + (r & 3) + 8 * (r >> 2) + 4 * hi;
          sm.qT[nl * 40 + l31] = f2bf(acc[Tl][r] + bq_);
        }
    } else {
      // k: direct scalar stores into kz (same layout as before)
      const float bk_ = bk[l31];
      const int kd = l31;
      const size_t kzb = (size_t)b * 131072;
      const size_t dbase = (size_t)(kd >> 4) * 512 + ((kd >> 3) & 1) * 256 + (kd & 7);
#pragma unroll
      for (int Tl = 0; Tl < 4; ++Tl) {
        const size_t Tg = (size_t)(nt * 8 + nh * 4 + Tl);
#pragma unroll
        for (int r = 0; r < 16; ++r) {
          int n31 = (r & 3) + 8 * (r >> 2) + 4 * hi;
          ko[kzb + Tg * 1024 + dbase + (size_t)n31 * 8] = f2bf(acc[Tl][r] + bk_);
        }
      }
    }
    __syncthreads();
    // all 256 threads: qT -> qs2 coalesced (64B per pixel row)
    {
      ushort* dst = qo + (size_t)b * 131072 + (size_t)(n0 + tid) * 32;
#pragma unroll
      for (int i = 0; i < 4; ++i)
        *(uint4*)(dst + i * 8) = *(const uint4*)&sm.qT[tid * 40 + i * 8];
    }
  } else {
    // v: direct stores into vz (ushort4, 512B-contiguous per wave instr)
    const float bv_ = bv[(dt - 1) * 64 + dh * 32 + l31];
    const int cu = (dt - 1) * 2 + dh;
    const size_t vzb = (size_t)b * 1048576;
#pragma unroll
    for (int Tl = 0; Tl < 4; ++Tl) {
      const size_t Tg = (size_t)(nt * 8 + nh * 4 + Tl);
#pragma unroll
      for (int g = 0; g < 4; ++g) {
        ushort4 w;
        w.x = f2bf(acc[Tl][g * 4 + 0] + bv_);
        w.y = f2bf(acc[Tl][g * 4 + 1] + bv_);
        w.z = f2bf(acc[Tl][g * 4 + 2] + bv_);
        w.w = f2bf(acc[Tl][g * 4 + 3] + bv_);
        size_t addr = vzb + Tg * 8192 + (size_t)(cu * 2 + (g >> 1)) * 512
                      + (size_t)(g & 1) * 256 + (size_t)l31 * 8 + 4 * hi;
        *(ushort4*)(vo + addr) = w;
      }
    }
  }
}

// ---------------------------------------------------------------------------
// online softmax + P pack only (no acc rescale — that goes through the afac
// all-to-all path). Returns rescale factor aa (1.0f if deferred).
// ---------------------------------------------------------------------------
static __device__ __forceinline__ float softmax_pack_only(
    f32x16& s, float& mrun, float& lsum, bf16x8& pb0o, bf16x8& pb1o)
{
  float pm = s[0];
#pragma unroll
  for (int r = 1; r < 16; ++r) pm = fmaxf(pm, s[r]);
  pm = fmaxf(pm, __shfl_xor(pm, 32));

  float aa = 1.0f;
  if (!__all(pm <= mrun + 8.0f)) {              // defer-max (T13), log2 domain
    float mnew = fmaxf(mrun, pm);
    aa = EXP2(mrun - mnew);
    mrun = mnew;
    lsum *= aa;
  }

  float p[16];
  float ps = 0.f;
#pragma unroll
  for (int r = 0; r < 16; ++r) { p[r] = EXP2(s[r] - mrun); ps += p[r]; }
  ps += __shfl_xor(ps, 32);
  lsum += ps;

  uint pw[8];
#pragma unroll
  for (int j = 0; j < 8; ++j) pw[j] = cvtpk_bf16(p[2 * j], p[2 * j + 1]);
  plswap(pw[0], pw[2]); plswap(pw[1], pw[3]);
  plswap(pw[4], pw[6]); plswap(pw[5], pw[7]);
  union { uint u[4]; bf16x8 v; } pb0u, pb1u;
  pb0u.u[0] = pw[0]; pb0u.u[1] = pw[1]; pb0u.u[2] = pw[2]; pb0u.u[3] = pw[3];
  pb1u.u[0] = pw[4]; pb1u.u[1] = pw[5]; pb1u.u[2] = pw[6]; pb1u.u[3] = pw[7];
  pb0o = pb0u.v; pb1o = pb1u.v;
  return aa;
}

// ---------------------------------------------------------------------------
// Kernel 2 v9.1: 8-wave all-to-all P-exchange flash attention + residual.
// Identical structure to R9 (118.8 us) with two surgical edits:
//  (a) Q loaded from qs2[m][32d] -> 2 x b128 instead of 16 scalar loads;
//  (b) pexch XOR swizzle idx = lane*8 ^ (lane&4) on BOTH write and read
//      (rule #21) -> kills the 6.3M 2-way bank conflicts.
// ---------------------------------------------------------------------------
__global__ __launch_bounds__(512, 2) void attn_fused(
    const ushort* __restrict__ qs, const ushort* __restrict__ kz,
    const ushort* __restrict__ vz, const float* __restrict__ x,
    const float* __restrict__ gamma, float* __restrict__ out)
{
  __shared__ __align__(16) union SMem {
    ushort vbuf[8][2][2048];        // per-wave V c-quarter, dbuf   64 KB
    float  xch[4][2][2][16][64];    // epilogue acc exchange        64 KB
  } sm;
  __shared__ __align__(16) ushort kbuf[2][4][1024];  // K 4-slot ring  16 KB
  __shared__ uint  pexch[2][2][4][64][8];            // packed P       32 KB
  __shared__ float afac[2][2][4][64];                // rescale         4 KB
  __shared__ float mlbuf[2][4][2][64];               // (m,l) final     4 KB

  const int wg = blockIdx.x;                      // 0..255
  const int swz = (wg & 7) * 32 + (wg >> 3);      // one batch per XCD
  const int b = swz >> 5, mt = swz & 31;
  const int tid = threadIdx.x;
  const int wv = tid >> 6, lane = tid & 63;
  const int kh = wv >> 2, q = wv & 3;
  const int l31 = lane & 31, hi = lane >> 5;
  const int mbase = mt * 128;
  const int mSelf = mbase + q * 32 + l31;

  // resident Q B-frags for mset q (qs2[m][32d] -> 2 x 16B loads)
  const ushort* qrow = qs + (size_t)b * 131072 + (size_t)mSelf * 32;
  bf16x8 qf0 = *(const bf16x8*)(qrow + 8 * hi);
  bf16x8 qf1 = *(const bf16x8*)(qrow + 16 + 8 * hi);

  const ushort* kb = kz + (size_t)b * 131072 + (size_t)kh * 64 * 1024;
  const ushort* vb = vz + (size_t)b * 1048576 + (size_t)kh * 64 * 8192;

  f32x16 acc[4][2];
#pragma unroll
  for (int mu = 0; mu < 4; ++mu)
#pragma unroll
    for (int cf = 0; cf < 2; ++cf)
#pragma unroll
      for (int r = 0; r < 16; ++r) acc[mu][cf][r] = 0.f;

  const f32x16 fzero = {};
  float mrun = -1e30f, lsum = 0.f;

  const int pswz = (lane * 8) ^ (lane & 4);       // pexch XOR swizzle

  // V: 4 gloads (c-quarter, 4KB) into private vbuf[wv][par]
  auto ISSUE_V = [&](int t, int par) {
#pragma unroll
    for (int i = 0; i < 4; ++i)
      gload16(vb + (size_t)t * 8192 + (size_t)(q * 4 + i) * 512 + lane * 8,
              &sm.vbuf[wv][par][i * 512]);
  };
  // K: waves q=0,1 each stage one 512-ushort frag into the 4-slot ring
  auto ISSUE_K = [&](int t) {
    if (q < 2)
      gload16(kb + (size_t)t * 1024 + (size_t)q * 512 + lane * 8,
              &kbuf[kh][t & 3][q * 512]);
  };

  // prologue: V(0) K(0) K(1) V(1) K(2)  [q<2: 11 ops, q>=2: 8 ops]
  ISSUE_V(0, 0);
  ISSUE_K(0);
  ISSUE_K(1);
  ISSUE_V(1, 1);
  ISSUE_K(2);
  if (q < 2) { asm volatile("s_waitcnt vmcnt(5)" ::: "memory"); }
  else       { asm volatile("s_waitcnt vmcnt(4)" ::: "memory"); }
  __builtin_amdgcn_s_barrier();   // certifies K(0) for all waves

#define BODY(T, W01, W23)                                                      \
  {                                                                            \
    const int t_ = (T);                                                        \
    const int vpar = t_ & 1, kslot = t_ & 3, xpar = t_ & 1;                    \
    if (q < 2) { asm volatile("s_waitcnt vmcnt(" #W01 ")" ::: "memory"); }     \
    else       { asm volatile("s_waitcnt vmcnt(" #W23 ")" ::: "memory"); }     \
    /* QK^T for mset q */                                                      \
    bf16x8 ka0 = *(const bf16x8*)&kbuf[kh][kslot][lane * 8];                   \
    bf16x8 ka1 = *(const bf16x8*)&kbuf[kh][kslot][512 + lane * 8];             \
    f32x16 s = __builtin_amdgcn_mfma_f32_32x32x16_bf16(ka0, qf0, fzero, 0, 0, 0); \
    s = __builtin_amdgcn_mfma_f32_32x32x16_bf16(ka1, qf1, s, 0, 0, 0);         \
    bf16x8 pbS0, pbS1;                                                         \
    float aa = softmax_pack_only(s, mrun, lsum, pbS0, pbS1);                   \
    { union { bf16x8 v; uint4 u; } c0, c1; c0.v = pbS0; c1.v = pbS1;           \
      uint* pp = &pexch[kh][xpar][q][0][0];                                    \
      *(uint4*)(pp + pswz) = c0.u;                                             \
      *(uint4*)(pp + (pswz ^ 4)) = c1.u; }                                     \
    afac[kh][xpar][q][lane] = aa;                                              \
    asm volatile("s_waitcnt lgkmcnt(0)" ::: "memory");                         \
    __builtin_amdgcn_s_barrier();                                              \
    /* V frags once, reused by all 4 msets */                                  \
    bf16x8 va0 = *(const bf16x8*)&sm.vbuf[wv][vpar][0 * 512 + lane * 8];       \
    bf16x8 va1 = *(const bf16x8*)&sm.vbuf[wv][vpar][1 * 512 + lane * 8];       \
    bf16x8 va2 = *(const bf16x8*)&sm.vbuf[wv][vpar][2 * 512 + lane * 8];       \
    bf16x8 va3 = *(const bf16x8*)&sm.vbuf[wv][vpar][3 * 512 + lane * 8];       \
    _Pragma("unroll")                                                          \
    for (int mu = 0; mu < 4; ++mu) {                                           \
      float aaU = afac[kh][xpar][mu][lane];                                    \
      uint* pr = &pexch[kh][xpar][mu][0][0];                                   \
      union { uint4 u; bf16x8 v; } r0, r1;                                     \
      r0.u = *(const uint4*)(pr + pswz);                                       \
      r1.u = *(const uint4*)(pr + (pswz ^ 4));                                 \
      if (!__all(aaU == 1.0f)) {                                               \
        _Pragma("unroll")                                                      \
        for (int cf = 0; cf < 2; ++cf)                                         \
          _Pragma("unroll")                                                    \
          for (int r = 0; r < 16; ++r) acc[mu][cf][r] *= aaU;                  \
      }                                                                        \
      __builtin_amdgcn_s_setprio(1);                                           \
      acc[mu][0] = __builtin_amdgcn_mfma_f32_32x32x16_bf16(va0, r0.v, acc[mu][0], 0, 0, 0); \
      acc[mu][0] = __builtin_amdgcn_mfma_f32_32x32x16_bf16(va1, r1.v, acc[mu][0], 0, 0, 0); \
      acc[mu][1] = __builtin_amdgcn_mfma_f32_32x32x16_bf16(va2, r0.v, acc[mu][1], 0, 0, 0); \
      acc[mu][1] = __builtin_amdgcn_mfma_f32_32x32x16_bf16(va3, r1.v, acc[mu][1], 0, 0, 0); \
      __builtin_amdgcn_s_setprio(0);                                           \
    }                                                                          \
    if (t_ < 62) ISSUE_V(t_ + 2, vpar);                                        \
    if (t_ < 61) ISSUE_K(t_ + 3);                                              \
  }

  for (int t = 0; t < 62; ++t) BODY(t, 5, 4);
  BODY(62, 4, 4);
  BODY(63, 0, 0);
#undef BODY

  // ---- epilogue: cross-kh merge ----
  mlbuf[kh][q][0][lane] = mrun;
  mlbuf[kh][q][1][lane] = lsum;
  asm volatile("s_waitcnt lgkmcnt(0)" ::: "memory");
  __builtin_amdgcn_s_barrier();

  const float g = gamma[0];
  const float* xc = x + (size_t)b * 256 * 4096;
  float* oc = out + (size_t)b * 256 * 4096;

  // pass A: msets 0,1 — kh1 ships, kh0 merges + stores
  if (kh == 1) {
#pragma unroll
    for (int mu = 0; mu < 2; ++mu)
#pragma unroll
      for (int cf = 0; cf < 2; ++cf)
#pragma unroll
        for (int r = 0; r < 16; ++r)
          sm.xch[q][mu][cf][r][lane] = acc[mu][cf][r];
  }
  asm volatile("s_waitcnt lgkmcnt(0)" ::: "memory");
  __builtin_amdgcn_s_barrier();
  if (kh == 0) {
#pragma unroll
    for (int mu = 0; mu < 2; ++mu) {
      float m0 = mlbuf[0][mu][0][lane], l0 = mlbuf[0][mu][1][lane];
      float m1 = mlbuf[1][mu][0][lane], l1 = mlbuf[1][mu][1][lane];
      float ms = fmaxf(m0, m1);
      float w0 = EXP2(m0 - ms), w1 = EXP2(m1 - ms);
      float inv = 1.0f / (l0 * w0 + l1 * w1);
      int m = mbase + mu * 32 + l31;
#pragma unroll
      for (int cf = 0; cf < 2; ++cf)
#pragma unroll
        for (int r = 0; r < 16; ++r) {
          float val = acc[mu][cf][r] * w0 + sm.xch[q][mu][cf][r][lane] * w1;
          int c = q * 64 + cf * 32 + (r & 3) + 8 * (r >> 2) + 4 * hi;
          oc[(size_t)c * 4096 + m] = g * (val * inv) + xc[(size_t)c * 4096 + m];
        }
    }
  }
  __builtin_amdgcn_s_barrier();
  // pass B: msets 2,3
  if (kh == 1) {
#pragma unroll
    for (int mu = 0; mu < 2; ++mu)
#pragma unroll
      for (int cf = 0; cf < 2; ++cf)
#pragma unroll
        for (int r = 0; r < 16; ++r)
          sm.xch[q][mu][cf][r][lane] = acc[2 + mu][cf][r];
  }
  asm volatile("s_waitcnt lgkmcnt(0)" ::: "memory");
  __builtin_amdgcn_s_barrier();
  if (kh == 0) {
#pragma unroll
    for (int mu = 0; mu < 2; ++mu) {
      float m0 = mlbuf[0][2 + mu][0][lane], l0 = mlbuf[0][2 + mu][1][lane];
      float m1 = mlbuf[1][2 + mu][0][lane], l1 = mlbuf[1][2 + mu][1][lane];
      float ms = fmaxf(m0, m1);
      float w0 = EXP2(m0 - ms), w1 = EXP2(m1 - ms);
      float inv = 1.0f / (l0 * w0 + l1 * w1);
      int m = mbase + (2 + mu) * 32 + l31;
#pragma unroll
      for (int cf = 0; cf < 2; ++cf)
#pragma unroll
        for (int r = 0; r < 16; ++r) {
          float val = acc[2 + mu][cf][r] * w0 + sm.xch[q][mu][cf][r][lane] * w1;
          int c = q * 64 + cf * 32 + (r & 3) + 8 * (r >> 2) + 4 * hi;
          oc[(size_t)c * 4096 + m] = g * (val * inv) + xc[(size_t)c * 4096 + m];
        }
    }
  }
}

extern "C" void kernel_launch(void* const* d_in, const int* in_sizes, int n_in,
                              void* d_out, int out_size, void* d_ws, size_t ws_size,
                              hipStream_t stream) {
  const float* x  = (const float*)d_in[0];
  const float* Wq = (const float*)d_in[1];
  const float* bq = (const float*)d_in[2];
  const float* Wk = (const float*)d_in[3];
  const float* bk = (const float*)d_in[4];
  const float* Wv = (const float*)d_in[5];
  const float* bv = (const float*)d_in[6];
  const float* gm = (const float*)d_in[7];
  float* out = (float*)d_out;

  ushort* qs = (ushort*)d_ws;                       // qs2[m][32d], 2 MB
  ushort* kzp = qs + (size_t)8 * 131072;
  ushort* vzp = kzp + (size_t)8 * 131072;

  proj_qkv<<<dim3(16, 8, 5), 256, 0, stream>>>(x, Wq, bq, Wk, bk, Wv, bv, qs, kzp, vzp);
  attn_fused<<<dim3(256), 512, 0, stream>>>(qs, kzp, vzp, x, gm, out);
}